// Round 4
// baseline (21056.052 us; speedup 1.0000x reference)
//
#include <hip/hip_runtime.h>

#define HID   1024
#define BATCH 256
#define TSEQ  128
#define PRED  96
#define IND   7
#define OUTD  7
#define SK    10   // small input dim: 7 features + 3 time-encode dims

typedef __attribute__((ext_vector_type(8))) _Float16 f16x8;
typedef __attribute__((ext_vector_type(4))) float    f32x4;

#define BM   64
#define BN   64
#define GSTR 68    // gates LDS stride (floats), <=2-way bank aliasing (free)

__device__ __forceinline__ float sigmoidf_fast(float x) {
  return 1.0f / (1.0f + __expf(-x));
}
__device__ __forceinline__ float tanhf_fast(float x) {
  float ax = fabsf(x);
  float e  = __expf(-2.0f * ax);
  float r  = (1.0f - e) / (1.0f + e);
  return copysignf(r, x);
}

__device__ __forceinline__ void async_cp16(const void* g, void* l) {
  __builtin_amdgcn_global_load_lds(
      (const __attribute__((address_space(1))) void*)g,
      (__attribute__((address_space(3))) void*)l, 16, 0, 0);
}

// fine-grained wait + barrier (pipeline): NEVER vmcnt(0) mid-loop
#define WBAR(N) asm volatile("s_waitcnt vmcnt(" #N ")\n\ts_barrier" ::: "memory")
#define BARO()  asm volatile("s_barrier" ::: "memory")

// device-wide barrier: monotonic counter, agent-scope atomics.
// Safe: grid=256 blocks, LDS>80KB forces 1 block/CU -> all co-resident.
__device__ __forceinline__ void gridbar(unsigned* bar, unsigned tgt) {
  __threadfence();                 // release: drain stores, wb L2
  __syncthreads();
  if (threadIdx.x == 0) {
    __hip_atomic_fetch_add(bar, 1u, __ATOMIC_ACQ_REL, __HIP_MEMORY_SCOPE_AGENT);
    while (__hip_atomic_load(bar, __ATOMIC_ACQUIRE, __HIP_MEMORY_SCOPE_AGENT) < tgt)
      __builtin_amdgcn_s_sleep(8);
  }
  __syncthreads();
  __threadfence();                 // acquire: invalidate L1/L2
}

// ---------------------------------------------------------------------------
// Weight prep: fp16 B [n][k], n = nb*64 + gate*16 + u <-> r = gate*1024+nb*16+u
// ---------------------------------------------------------------------------
__global__ __launch_bounds__(256) void prep_kernel(
    const float* __restrict__ Wih0, const float* __restrict__ Whh0,
    const float* __restrict__ bih0, const float* __restrict__ bhh0,
    const float* __restrict__ Wih1, const float* __restrict__ Whh1,
    const float* __restrict__ bih1, const float* __restrict__ bhh1,
    const float* __restrict__ Wih2, const float* __restrict__ Whh2,
    const float* __restrict__ bih2, const float* __restrict__ bhh2,
    _Float16* __restrict__ B0, _Float16* __restrict__ B1, _Float16* __restrict__ B2,
    float* __restrict__ W0p, float* __restrict__ biasP)
{
  size_t e = (size_t)blockIdx.x * 256 + threadIdx.x;
  const size_t S0 = (size_t)4096 * 1024;
  const size_t S1 = (size_t)4096 * 2048;
  if (e < S0) {
    int n = (int)(e >> 10), k = (int)(e & 1023);
    int nb = n >> 6, gate = (n >> 4) & 3, u = n & 15;
    int r = gate * 1024 + nb * 16 + u;
    B0[e] = (_Float16)Whh0[(size_t)r * 1024 + k];
  } else if (e < S0 + S1) {
    size_t q = e - S0;
    int n = (int)(q >> 11), k = (int)(q & 2047);
    int nb = n >> 6, gate = (n >> 4) & 3, u = n & 15;
    int r = gate * 1024 + nb * 16 + u;
    float v = (k < 1024) ? Wih1[(size_t)r * 1024 + k]
                         : Whh1[(size_t)r * 1024 + (k - 1024)];
    B1[q] = (_Float16)v;
  } else if (e < S0 + 2 * S1) {
    size_t q = e - S0 - S1;
    int n = (int)(q >> 11), k = (int)(q & 2047);
    int nb = n >> 6, gate = (n >> 4) & 3, u = n & 15;
    int r = gate * 1024 + nb * 16 + u;
    float v = (k < 1024) ? Wih2[(size_t)r * 1024 + k]
                         : Whh2[(size_t)r * 1024 + (k - 1024)];
    B2[q] = (_Float16)v;
  } else if (e < S0 + 2 * S1 + 40960) {
    int q = (int)(e - S0 - 2 * S1);
    int n = q / 10, k = q - n * 10;
    int nb = n >> 6, gate = (n >> 4) & 3, u = n & 15;
    int r = gate * 1024 + nb * 16 + u;
    W0p[q] = Wih0[(size_t)r * 10 + k];
  } else if (e < S0 + 2 * S1 + 40960 + 12288) {
    int q = (int)(e - S0 - 2 * S1 - 40960);
    int l = q >> 12, n = q & 4095;
    int nb = n >> 6, gate = (n >> 4) & 3, u = n & 15;
    int r = gate * 1024 + nb * 16 + u;
    const float* bi = (l == 0) ? bih0 : (l == 1) ? bih1 : bih2;
    const float* bh = (l == 0) ? bhh0 : (l == 1) ? bhh1 : bhh2;
    biasP[q] = bi[r] + bh[r];
  }
}

// ---------------------------------------------------------------------------
// Encoder wavefront kernel (unchanged from R3): dispatch d computes
// L0@t=d, L1@t=d-1, L2@t=d-2. Grid (64, 12), 3 blocks/CU.
// ---------------------------------------------------------------------------
__global__ __launch_bounds__(256) void lstm_wave(
    int d,
    _Float16* __restrict__ h0p0, _Float16* __restrict__ h0p1,
    _Float16* __restrict__ h1p0, _Float16* __restrict__ h1p1,
    _Float16* __restrict__ h2p0, _Float16* __restrict__ h2p1,
    const _Float16* __restrict__ B0g, const _Float16* __restrict__ B1g,
    const _Float16* __restrict__ B2g,
    const float* __restrict__ biasP, const float* __restrict__ W0p,
    float* __restrict__ c0, float* __restrict__ c1, float* __restrict__ c2,
    const float* __restrict__ x, const int* __restrict__ xte,
    const float* __restrict__ e0, const float* __restrict__ e1,
    const float* __restrict__ e2, const float* __restrict__ e3)
{
  __shared__ __align__(16) char smem[32768];
  __shared__ float SmallIn[BM * SK];
  __shared__ float W0s[BN * 11];

  const int layer = blockIdx.y >> 2;
  const int mb = blockIdx.y & 3, nb = blockIdx.x;
  const int t = d - layer;
  if (t < 0 || t >= TSEQ) return;
  const int p = d & 1;

  const _Float16 *A1, *A2; _Float16* ho; const _Float16* Bm;
  const float* bias; float* cst; int Kdim;
  if (layer == 0) {
    A1 = p ? h0p1 : h0p0; A2 = A1;              ho = p ? h0p0 : h0p1;
    Bm = B0g; bias = biasP;        cst = c0; Kdim = 1024;
  } else if (layer == 1) {
    A1 = p ? h0p1 : h0p0; A2 = p ? h1p1 : h1p0; ho = p ? h1p0 : h1p1;
    Bm = B1g; bias = biasP + 4096; cst = c1; Kdim = 2048;
  } else {
    A1 = p ? h1p1 : h1p0; A2 = p ? h2p1 : h2p0; ho = p ? h2p0 : h2p1;
    Bm = B2g; bias = biasP + 8192; cst = c2; Kdim = 2048;
  }
  const int Mbase = mb * BM;
  const int tid = threadIdx.x;

  if (layer == 0 && tid < BM) {
    int Mg = Mbase + tid;
    float v[SK];
    const float* xp = x + ((size_t)Mg * TSEQ + t) * IND;
#pragma unroll
    for (int i = 0; i < IND; ++i) v[i] = xp[i];
    const int* ip = xte + ((size_t)Mg * TSEQ + t) * 4;
    int i0 = ip[0], i1 = ip[1], i2 = ip[2], i3 = ip[3];
#pragma unroll
    for (int dd = 0; dd < 3; ++dd)
      v[IND + dd] = e0[i0 * 3 + dd] + e1[i1 * 3 + dd] + e2[i2 * 3 + dd] + e3[i3 * 3 + dd];
#pragma unroll
    for (int i = 0; i < SK; ++i) SmallIn[tid * SK + i] = v[i];
    const float* wp = W0p + (size_t)(nb * BN + tid) * SK;
#pragma unroll
    for (int i = 0; i < SK; ++i) W0s[tid * 11 + i] = wp[i];
  }

  _Float16* As = (_Float16*)smem;
  _Float16* Bs = (_Float16*)(smem + 16384);

  const int w = tid >> 6, lane = tid & 63;
  const int quad = lane >> 4, l16 = lane & 15;
  const int dr = lane >> 4, ds = lane & 15;

  size_t a_goff[4], b_goff[4];
  int lds_off[4];
#pragma unroll
  for (int i = 0; i < 4; ++i) {
    int lrow = w * 16 + i * 4 + dr;
    int sg = ds ^ (i * 4 + dr);
    a_goff[i] = (size_t)(Mbase + lrow) * (HID * 2) + (size_t)sg * 16;
    b_goff[i] = (size_t)(nb * BN + lrow) * ((size_t)Kdim * 2) + (size_t)sg * 16;
    lds_off[i] = lrow * 256 + ds * 16;
  }

  f32x4 acc[4] = {};

  for (int kk = 0; kk < Kdim; kk += 128) {
    const char* Abase = (kk < 1024)
        ? ((const char*)A1 + (size_t)kk * 2)
        : ((const char*)A2 + (size_t)(kk - 1024) * 2);
    const char* Bbase = (const char*)Bm + (size_t)kk * 2;
#pragma unroll
    for (int i = 0; i < 4; ++i) {
      async_cp16(Abase + a_goff[i], smem + lds_off[i]);
      async_cp16(Bbase + b_goff[i], smem + 16384 + lds_off[i]);
    }
    __syncthreads();
#pragma unroll
    for (int ks = 0; ks < 4; ++ks) {
      int segq = (ks * 4 + quad) ^ l16;
      f16x8 bf = *reinterpret_cast<const f16x8*>(Bs + (w * 16 + l16) * 128 + segq * 8);
#pragma unroll
      for (int mt = 0; mt < 4; ++mt) {
        f16x8 af = *reinterpret_cast<const f16x8*>(As + (mt * 16 + l16) * 128 + segq * 8);
        acc[mt] = __builtin_amdgcn_mfma_f32_16x16x32_f16(af, bf, acc[mt], 0, 0, 0);
      }
    }
    __syncthreads();
  }

  float* Gs = (float*)smem;
#pragma unroll
  for (int mt = 0; mt < 4; ++mt) {
    int row = mt * 16 + quad * 4;
    int col = w * 16 + l16;
#pragma unroll
    for (int r = 0; r < 4; ++r)
      Gs[(row + r) * GSTR + col] = acc[mt][r];
  }
  __syncthreads();

#pragma unroll
  for (int i = 0; i < 4; ++i) {
    int m = (tid >> 4) + i * 16;
    int u = tid & 15;
    float gi = Gs[m * GSTR + u];
    float gf = Gs[m * GSTR + 16 + u];
    float gg = Gs[m * GSTR + 32 + u];
    float go = Gs[m * GSTR + 48 + u];
    int nbase = nb * BN;
    gi += bias[nbase + u];
    gf += bias[nbase + 16 + u];
    gg += bias[nbase + 32 + u];
    go += bias[nbase + 48 + u];
    if (layer == 0) {
#pragma unroll
      for (int k = 0; k < SK; ++k) {
        float sv = SmallIn[m * SK + k];
        gi += sv * W0s[u * 11 + k];
        gf += sv * W0s[(16 + u) * 11 + k];
        gg += sv * W0s[(32 + u) * 11 + k];
        go += sv * W0s[(48 + u) * 11 + k];
      }
    }
    size_t cidx = (size_t)(Mbase + m) * HID + (size_t)nb * 16 + u;
    float cold = cst[cidx];
    float cn = sigmoidf_fast(gf) * cold + sigmoidf_fast(gi) * tanhf_fast(gg);
    float hn = sigmoidf_fast(go) * tanhf_fast(cn);
    cst[cidx] = cn;
    ho[cidx] = (_Float16)hn;
  }
}

// ---------------------------------------------------------------------------
// Persistent-decoder layer body. BK=128 chunks, 3x32KB LDS bufs, depth-2,
// fine-grained vmcnt. MODE 1: L0 (+small input). MODE 2: deep. MODE 3: deep
// + fused fc -> atomicAdd out[:, s+1, :].
// ---------------------------------------------------------------------------
template<int KC, int MODE>
__device__ __forceinline__ void dec_layer(
    const char* A1, const char* A2, const char* Bm,
    const int* a_off, const int* b_off, const int* l_off,
    char* smem, float* Gs, const float* SmallIn, const float* W0s,
    const float* biasg, float* creg, _Float16* hout, float* out,
    const float* w7, const float* fcadd, int s, int Mbase, int nb, int tid)
{
  const int w = tid >> 6, lane = tid & 63;
  const int quad = lane >> 4, l16 = lane & 15;
  f32x4 acc[4] = {};

#define DISSUE(c) do { \
    const char* Ab_ = (KC == 8 || (c) < 8) ? (A1 + (size_t)(c) * 256) \
                                           : (A2 + (size_t)((c) - 8) * 256); \
    const char* Bb_ = Bm + (size_t)(c) * 256; \
    char* Lb_ = smem + ((c) % 3) * 32768; \
    _Pragma("unroll") \
    for (int i_ = 0; i_ < 4; ++i_) { \
      async_cp16(Ab_ + a_off[i_], Lb_ + l_off[i_]); \
      async_cp16(Bb_ + b_off[i_], Lb_ + 16384 + l_off[i_]); \
    } } while (0)

  DISSUE(0);
  DISSUE(1);
#pragma unroll
  for (int c = 0; c < KC; ++c) {
    if (c + 2 < KC)       { DISSUE(c + 2); WBAR(16); }
    else if (c + 2 == KC) { WBAR(8); }
    else                  { WBAR(0); }
    const _Float16* As = (const _Float16*)(smem + (c % 3) * 32768);
    const _Float16* Bs = As + 8192;
#pragma unroll
    for (int ks = 0; ks < 4; ++ks) {
      int sq = (ks * 4 + quad) ^ l16;
      f16x8 bf = *reinterpret_cast<const f16x8*>(Bs + (w * 16 + l16) * 128 + sq * 8);
#pragma unroll
      for (int mt = 0; mt < 4; ++mt) {
        f16x8 af = *reinterpret_cast<const f16x8*>(As + (mt * 16 + l16) * 128 + sq * 8);
        acc[mt] = __builtin_amdgcn_mfma_f32_16x16x32_f16(af, bf, acc[mt], 0, 0, 0);
      }
    }
    BARO();   // buffer-recycle guard
  }
#undef DISSUE

#pragma unroll
  for (int mt = 0; mt < 4; ++mt) {
    int row = mt * 16 + quad * 4;
    int col = w * 16 + l16;
#pragma unroll
    for (int r = 0; r < 4; ++r)
      Gs[(row + r) * GSTR + col] = acc[mt][r];
  }
  __syncthreads();

#pragma unroll
  for (int i = 0; i < 4; ++i) {
    int m = (tid >> 4) + i * 16;
    int u = tid & 15;
    float gi = Gs[m * GSTR + u]      + biasg[0];
    float gf = Gs[m * GSTR + 16 + u] + biasg[1];
    float gg = Gs[m * GSTR + 32 + u] + biasg[2];
    float go = Gs[m * GSTR + 48 + u] + biasg[3];
    if (MODE == 1) {
#pragma unroll
      for (int k = 0; k < SK; ++k) {
        float sv = SmallIn[m * SK + k];
        gi += sv * W0s[u * 11 + k];
        gf += sv * W0s[(16 + u) * 11 + k];
        gg += sv * W0s[(32 + u) * 11 + k];
        go += sv * W0s[(48 + u) * 11 + k];
      }
    }
    float cn = sigmoidf_fast(gf) * creg[i] + sigmoidf_fast(gi) * tanhf_fast(gg);
    float hn = sigmoidf_fast(go) * tanhf_fast(cn);
    creg[i] = cn;
    hout[(size_t)(Mbase + m) * HID + (size_t)nb * 16 + u] = (_Float16)hn;
    if (MODE == 3) {
#pragma unroll
      for (int o = 0; o < OUTD; ++o) {
        float r = hn * w7[o];
        r += __shfl_xor(r, 1, 16);
        r += __shfl_xor(r, 2, 16);
        r += __shfl_xor(r, 4, 16);
        r += __shfl_xor(r, 8, 16);
        if (u == 0)
          atomicAdd(&out[(size_t)(Mbase + m) * (PRED * OUTD) + (s + 1) * OUTD + o],
                    r + fcadd[o]);
      }
    }
  }
}

// ---------------------------------------------------------------------------
// Persistent decoder: ONE kernel runs all 95 steps x 3 layers with
// device-wide barriers. Grid 256 blocks (nb = id&63 -> XCD-stable),
// LDS 121KB -> 1 block/CU -> all blocks co-resident (manual barrier safe).
// c-state, bias, fcW slice live in registers across all steps.
// ---------------------------------------------------------------------------
__global__ __launch_bounds__(256, 1) void lstm_dec(
    _Float16* __restrict__ h0a, _Float16* __restrict__ h0b,
    _Float16* __restrict__ h1a, _Float16* __restrict__ h1b,
    _Float16* __restrict__ h2a, _Float16* __restrict__ h2b,
    const _Float16* __restrict__ B0g, const _Float16* __restrict__ B1g,
    const _Float16* __restrict__ B2g,
    const float* __restrict__ biasP, const float* __restrict__ W0p,
    const float* __restrict__ cbuf,
    float* __restrict__ out, const int* __restrict__ yte,
    const float* __restrict__ e0, const float* __restrict__ e1,
    const float* __restrict__ e2, const float* __restrict__ e3,
    const float* __restrict__ fcW, const float* __restrict__ fcb,
    unsigned* __restrict__ bar)
{
  __shared__ __align__(16) char smem[3 * 32768];   // 96 KB staging
  __shared__ float Gs[BM * GSTR];                  // 17 KB
  __shared__ float SmallIn[BM * SK];
  __shared__ float W0s[BN * 11];

  const int tid = threadIdx.x;
  const int nb = blockIdx.x & 63, mb = blockIdx.x >> 6;
  const int Mbase = mb * BM;
  const int w = tid >> 6, lane = tid & 63;
  const int dr = lane >> 4, ds = lane & 15;

  int a_off[4], b1_off[4], b2_off[4], l_off[4];
#pragma unroll
  for (int i = 0; i < 4; ++i) {
    int lrow = w * 16 + i * 4 + dr;
    int sg = ds ^ (i * 4 + dr);
    a_off[i]  = (Mbase + lrow) * 2048 + sg * 16;
    b1_off[i] = (nb * 64 + lrow) * 2048 + sg * 16;
    b2_off[i] = (nb * 64 + lrow) * 4096 + sg * 16;
    l_off[i]  = lrow * 256 + ds * 16;
  }

  if (tid < BN) {
    const float* wp = W0p + (size_t)(nb * BN + tid) * SK;
#pragma unroll
    for (int i = 0; i < SK; ++i) W0s[tid * 11 + i] = wp[i];
  }

  const int u = tid & 15;
  float biasr[3][4];
#pragma unroll
  for (int l = 0; l < 3; ++l)
#pragma unroll
    for (int g = 0; g < 4; ++g)
      biasr[l][g] = biasP[l * 4096 + nb * 64 + g * 16 + u];

  float creg[3][4];
#pragma unroll
  for (int l = 0; l < 3; ++l)
#pragma unroll
    for (int i = 0; i < 4; ++i) {
      int m = (tid >> 4) + i * 16;
      creg[l][i] = cbuf[(size_t)l * 262144 + (size_t)(Mbase + m) * HID + nb * 16 + u];
    }

  float w7[OUTD], fcadd[OUTD];
#pragma unroll
  for (int o = 0; o < OUTD; ++o) {
    w7[o] = fcW[(size_t)o * HID + nb * 16 + u];
    fcadd[o] = (nb == 0) ? fcb[o] : 0.0f;
  }

  _Float16* h0[2] = {h0a, h0b};
  _Float16* h1[2] = {h1a, h1b};
  _Float16* h2[2] = {h2a, h2b};
  int p0 = 0, p1 = 1, p2 = 0;   // encoder handoff parities
  unsigned bc = 0;

  for (int s = 0; s < PRED - 1; ++s) {
    // small input for L0 (reads y_s from out, written by prev step / fc_kernel)
    if (tid < BM) {
      int Mg = Mbase + tid;
      float v[SK];
      const float* yp = out + (size_t)Mg * (PRED * OUTD) + s * OUTD;
#pragma unroll
      for (int i = 0; i < OUTD; ++i) v[i] = yp[i];
      const int* ip = yte + ((size_t)Mg * PRED + s) * 4;
      int i0 = ip[0], i1 = ip[1], i2 = ip[2], i3 = ip[3];
#pragma unroll
      for (int dd = 0; dd < 3; ++dd)
        v[IND + dd] = e0[i0 * 3 + dd] + e1[i1 * 3 + dd] + e2[i2 * 3 + dd] + e3[i3 * 3 + dd];
#pragma unroll
      for (int i = 0; i < SK; ++i) SmallIn[tid * SK + i] = v[i];
    }

    dec_layer<8, 1>((const char*)h0[p0], (const char*)h0[p0], (const char*)B0g,
                    a_off, b1_off, l_off, smem, Gs, SmallIn, W0s,
                    biasr[0], creg[0], h0[1 - p0], out, w7, fcadd, s, Mbase, nb, tid);
    gridbar(bar, ++bc * 256);

    dec_layer<16, 2>((const char*)h0[1 - p0], (const char*)h1[p1], (const char*)B1g,
                     a_off, b2_off, l_off, smem, Gs, SmallIn, W0s,
                     biasr[1], creg[1], h1[1 - p1], out, w7, fcadd, s, Mbase, nb, tid);
    gridbar(bar, ++bc * 256);

    dec_layer<16, 3>((const char*)h1[1 - p1], (const char*)h2[p2], (const char*)B2g,
                     a_off, b2_off, l_off, smem, Gs, SmallIn, W0s,
                     biasr[2], creg[2], h2[1 - p2], out, w7, fcadd, s, Mbase, nb, tid);
    gridbar(bar, ++bc * 256);

    p0 ^= 1; p1 ^= 1; p2 ^= 1;
  }
}

// ---------------------------------------------------------------------------
// Standalone FC head for y0 only: y = h2 @ fcW^T + fcb -> out[:,0,:].
// ---------------------------------------------------------------------------
__global__ __launch_bounds__(256) void fc_kernel(
    const _Float16* __restrict__ h2, const float* __restrict__ fcW,
    const float* __restrict__ fcb, float* __restrict__ out)
{
  int wv = threadIdx.x >> 6, lane = threadIdx.x & 63;
  int row = blockIdx.x * 4 + wv;
  const _Float16* hp = h2 + (size_t)row * HID + lane * 16;
  float hv[16];
#pragma unroll
  for (int i = 0; i < 16; ++i) hv[i] = (float)hp[i];
  float acc[OUTD];
#pragma unroll
  for (int o = 0; o < OUTD; ++o) {
    const float* wp = fcW + (size_t)o * HID + lane * 16;
    float a = 0.f;
#pragma unroll
    for (int i = 0; i < 16; ++i) a += hv[i] * wp[i];
    acc[o] = a;
  }
#pragma unroll
  for (int o = 0; o < OUTD; ++o)
#pragma unroll
    for (int off = 32; off >= 1; off >>= 1)
      acc[o] += __shfl_xor(acc[o], off, 64);
  if (lane == 0) {
#pragma unroll
    for (int o = 0; o < OUTD; ++o)
      out[(size_t)row * (PRED * OUTD) + o] = acc[o] + fcb[o];
  }
}

// ---------------------------------------------------------------------------
// Workspace layout (bytes):
//   B0 @0 (8 MB) | B1 @8388608 (16 MB) | B2 @25165824 (16 MB)
//   W0p @41943040 | biasP @42106880
//   h par0 @42156032 (1.5 MB) + c @43728896 (3 MB)  } one memset
//   h par1 @46874624 (1.5 MB)                        } second memset
//   bar @48447488 (4 B)
// ---------------------------------------------------------------------------
extern "C" void kernel_launch(void* const* d_in, const int* in_sizes, int n_in,
                              void* d_out, int out_size, void* d_ws, size_t ws_size,
                              hipStream_t stream) {
  const float* x   = (const float*)d_in[0];
  const int*   xte = (const int*)d_in[2];
  const int*   yte = (const int*)d_in[3];
  const float* e0  = (const float*)d_in[4];
  const float* e1  = (const float*)d_in[5];
  const float* e2  = (const float*)d_in[6];
  const float* e3  = (const float*)d_in[7];
  const float* Wih0 = (const float*)d_in[8];
  const float* Whh0 = (const float*)d_in[9];
  const float* bih0 = (const float*)d_in[10];
  const float* bhh0 = (const float*)d_in[11];
  const float* Wih1 = (const float*)d_in[12];
  const float* Whh1 = (const float*)d_in[13];
  const float* bih1 = (const float*)d_in[14];
  const float* bhh1 = (const float*)d_in[15];
  const float* Wih2 = (const float*)d_in[16];
  const float* Whh2 = (const float*)d_in[17];
  const float* bih2 = (const float*)d_in[18];
  const float* bhh2 = (const float*)d_in[19];
  const float* fcW = (const float*)d_in[20];
  const float* fcb = (const float*)d_in[21];
  float* out = (float*)d_out;

  char* ws = (char*)d_ws;
  _Float16* B0   = (_Float16*)(ws);
  _Float16* B1   = (_Float16*)(ws + 8388608);
  _Float16* B2   = (_Float16*)(ws + 25165824);
  float*    W0p  = (float*)(ws + 41943040);
  float*    biasP= (float*)(ws + 42106880);
  char*     hp0  = ws + 42156032;
  float*    cbuf = (float*)(ws + 43728896);
  char*     hp1  = ws + 46874624;
  unsigned* bar  = (unsigned*)(ws + 48447488);

  hipMemsetAsync(out, 0, (size_t)out_size * 4, stream);
  hipMemsetAsync(hp0, 0, 4718592, stream);
  hipMemsetAsync(hp1, 0, 1572864, stream);
  hipMemsetAsync(bar, 0, 4, stream);

  prep_kernel<<<82128, 256, 0, stream>>>(Wih0, Whh0, bih0, bhh0,
                                         Wih1, Whh1, bih1, bhh1,
                                         Wih2, Whh2, bih2, bhh2,
                                         B0, B1, B2, W0p, biasP);

  auto hb = [&](int l, int par) -> _Float16* {
    return (_Float16*)((par ? hp1 : hp0) + (size_t)l * 524288);
  };
  float* cl[3] = {cbuf, cbuf + 262144, cbuf + 524288};

  // encoder: wavefront over (layer, t) diagonals
  for (int d = 0; d < TSEQ + 2; ++d) {
    lstm_wave<<<dim3(64, 12), 256, 0, stream>>>(
        d, hb(0,0), hb(0,1), hb(1,0), hb(1,1), hb(2,0), hb(2,1),
        B0, B1, B2, biasP, W0p, cl[0], cl[1], cl[2],
        x, xte, e0, e1, e2, e3);
  }

  // handoff parities: h0@127 -> par0, h1@127 -> par1, h2@127 -> par0
  fc_kernel<<<64, 256, 0, stream>>>(hb(2,0), fcW, fcb, out);   // y0

  lstm_dec<<<256, 256, 0, stream>>>(
      hb(0,0), hb(0,1), hb(1,0), hb(1,1), hb(2,0), hb(2,1),
      B0, B1, B2, biasP, W0p, cbuf,
      out, yte, e0, e1, e2, e3, fcW, fcb, bar);
}

// Round 5
// 19674.777 us; speedup vs baseline: 1.0702x; 1.0702x over previous
//
#include <hip/hip_runtime.h>

#define HID   1024
#define BATCH 256
#define TSEQ  128
#define PRED  96
#define IND   7
#define OUTD  7
#define SK    10   // small input dim: 7 features + 3 time-encode dims

typedef __attribute__((ext_vector_type(8))) _Float16 f16x8;
typedef __attribute__((ext_vector_type(4))) float    f32x4;

#define BM   64
#define BN   64
#define GSTR 68    // gates LDS stride (floats), <=2-way bank aliasing (free)

__device__ __forceinline__ float sigmoidf_fast(float x) {
  return 1.0f / (1.0f + __expf(-x));
}
__device__ __forceinline__ float tanhf_fast(float x) {
  float ax = fabsf(x);
  float e  = __expf(-2.0f * ax);
  float r  = (1.0f - e) / (1.0f + e);
  return copysignf(r, x);
}

__device__ __forceinline__ void async_cp16(const void* g, void* l) {
  __builtin_amdgcn_global_load_lds(
      (const __attribute__((address_space(1))) void*)g,
      (__attribute__((address_space(3))) void*)l, 16, 0, 0);
}

// fine-grained wait + barrier (pipeline): NEVER vmcnt(0) mid-loop
#define WBAR(N) asm volatile("s_waitcnt vmcnt(" #N ")\n\ts_barrier" ::: "memory")
#define BARO()  asm volatile("s_barrier" ::: "memory")

// Device-wide barrier, RELAXED poll (critical: an ACQUIRE agent-scope load
// emits buffer_inv (L2 invalidate) PER POLL on gfx950 -> R4's 2.4x regression).
// Release = one __threadfence before add; acquire = one __threadfence after
// the spin exits. Safe: 256 blocks, 121KB LDS -> 1 block/CU -> co-resident.
__device__ __forceinline__ void gridbar(unsigned* bar, unsigned tgt) {
  __threadfence();                 // release: publish h/c/out stores
  __syncthreads();
  if (threadIdx.x == 0) {
    __hip_atomic_fetch_add(bar, 1u, __ATOMIC_RELAXED, __HIP_MEMORY_SCOPE_AGENT);
    while (__hip_atomic_load(bar, __ATOMIC_RELAXED, __HIP_MEMORY_SCOPE_AGENT) < tgt)
      __builtin_amdgcn_s_sleep(2);
  }
  __syncthreads();
  __threadfence();                 // acquire: one L2 inv per block per barrier
}

// ---------------------------------------------------------------------------
// Weight prep: fp16 B [n][k], n = nb*64 + gate*16 + u <-> r = gate*1024+nb*16+u
// ---------------------------------------------------------------------------
__global__ __launch_bounds__(256) void prep_kernel(
    const float* __restrict__ Wih0, const float* __restrict__ Whh0,
    const float* __restrict__ bih0, const float* __restrict__ bhh0,
    const float* __restrict__ Wih1, const float* __restrict__ Whh1,
    const float* __restrict__ bih1, const float* __restrict__ bhh1,
    const float* __restrict__ Wih2, const float* __restrict__ Whh2,
    const float* __restrict__ bih2, const float* __restrict__ bhh2,
    _Float16* __restrict__ B0, _Float16* __restrict__ B1, _Float16* __restrict__ B2,
    float* __restrict__ W0p, float* __restrict__ biasP)
{
  size_t e = (size_t)blockIdx.x * 256 + threadIdx.x;
  const size_t S0 = (size_t)4096 * 1024;
  const size_t S1 = (size_t)4096 * 2048;
  if (e < S0) {
    int n = (int)(e >> 10), k = (int)(e & 1023);
    int nb = n >> 6, gate = (n >> 4) & 3, u = n & 15;
    int r = gate * 1024 + nb * 16 + u;
    B0[e] = (_Float16)Whh0[(size_t)r * 1024 + k];
  } else if (e < S0 + S1) {
    size_t q = e - S0;
    int n = (int)(q >> 11), k = (int)(q & 2047);
    int nb = n >> 6, gate = (n >> 4) & 3, u = n & 15;
    int r = gate * 1024 + nb * 16 + u;
    float v = (k < 1024) ? Wih1[(size_t)r * 1024 + k]
                         : Whh1[(size_t)r * 1024 + (k - 1024)];
    B1[q] = (_Float16)v;
  } else if (e < S0 + 2 * S1) {
    size_t q = e - S0 - S1;
    int n = (int)(q >> 11), k = (int)(q & 2047);
    int nb = n >> 6, gate = (n >> 4) & 3, u = n & 15;
    int r = gate * 1024 + nb * 16 + u;
    float v = (k < 1024) ? Wih2[(size_t)r * 1024 + k]
                         : Whh2[(size_t)r * 1024 + (k - 1024)];
    B2[q] = (_Float16)v;
  } else if (e < S0 + 2 * S1 + 40960) {
    int q = (int)(e - S0 - 2 * S1);
    int n = q / 10, k = q - n * 10;
    int nb = n >> 6, gate = (n >> 4) & 3, u = n & 15;
    int r = gate * 1024 + nb * 16 + u;
    W0p[q] = Wih0[(size_t)r * 10 + k];
  } else if (e < S0 + 2 * S1 + 40960 + 12288) {
    int q = (int)(e - S0 - 2 * S1 - 40960);
    int l = q >> 12, n = q & 4095;
    int nb = n >> 6, gate = (n >> 4) & 3, u = n & 15;
    int r = gate * 1024 + nb * 16 + u;
    const float* bi = (l == 0) ? bih0 : (l == 1) ? bih1 : bih2;
    const float* bh = (l == 0) ? bhh0 : (l == 1) ? bhh1 : bhh2;
    biasP[q] = bi[r] + bh[r];
  }
}

// ---------------------------------------------------------------------------
// Encoder wavefront kernel: dispatch d computes L0@t=d, L1@t=d-1, L2@t=d-2.
// Grid (64, 12), 3 blocks/CU.
// ---------------------------------------------------------------------------
__global__ __launch_bounds__(256) void lstm_wave(
    int d,
    _Float16* __restrict__ h0p0, _Float16* __restrict__ h0p1,
    _Float16* __restrict__ h1p0, _Float16* __restrict__ h1p1,
    _Float16* __restrict__ h2p0, _Float16* __restrict__ h2p1,
    const _Float16* __restrict__ B0g, const _Float16* __restrict__ B1g,
    const _Float16* __restrict__ B2g,
    const float* __restrict__ biasP, const float* __restrict__ W0p,
    float* __restrict__ c0, float* __restrict__ c1, float* __restrict__ c2,
    const float* __restrict__ x, const int* __restrict__ xte,
    const float* __restrict__ e0, const float* __restrict__ e1,
    const float* __restrict__ e2, const float* __restrict__ e3)
{
  __shared__ __align__(16) char smem[32768];
  __shared__ float SmallIn[BM * SK];
  __shared__ float W0s[BN * 11];

  const int layer = blockIdx.y >> 2;
  const int mb = blockIdx.y & 3, nb = blockIdx.x;
  const int t = d - layer;
  if (t < 0 || t >= TSEQ) return;
  const int p = d & 1;

  const _Float16 *A1, *A2; _Float16* ho; const _Float16* Bm;
  const float* bias; float* cst; int Kdim;
  if (layer == 0) {
    A1 = p ? h0p1 : h0p0; A2 = A1;              ho = p ? h0p0 : h0p1;
    Bm = B0g; bias = biasP;        cst = c0; Kdim = 1024;
  } else if (layer == 1) {
    A1 = p ? h0p1 : h0p0; A2 = p ? h1p1 : h1p0; ho = p ? h1p0 : h1p1;
    Bm = B1g; bias = biasP + 4096; cst = c1; Kdim = 2048;
  } else {
    A1 = p ? h1p1 : h1p0; A2 = p ? h2p1 : h2p0; ho = p ? h2p0 : h2p1;
    Bm = B2g; bias = biasP + 8192; cst = c2; Kdim = 2048;
  }
  const int Mbase = mb * BM;
  const int tid = threadIdx.x;

  if (layer == 0 && tid < BM) {
    int Mg = Mbase + tid;
    float v[SK];
    const float* xp = x + ((size_t)Mg * TSEQ + t) * IND;
#pragma unroll
    for (int i = 0; i < IND; ++i) v[i] = xp[i];
    const int* ip = xte + ((size_t)Mg * TSEQ + t) * 4;
    int i0 = ip[0], i1 = ip[1], i2 = ip[2], i3 = ip[3];
#pragma unroll
    for (int dd = 0; dd < 3; ++dd)
      v[IND + dd] = e0[i0 * 3 + dd] + e1[i1 * 3 + dd] + e2[i2 * 3 + dd] + e3[i3 * 3 + dd];
#pragma unroll
    for (int i = 0; i < SK; ++i) SmallIn[tid * SK + i] = v[i];
    const float* wp = W0p + (size_t)(nb * BN + tid) * SK;
#pragma unroll
    for (int i = 0; i < SK; ++i) W0s[tid * 11 + i] = wp[i];
  }

  _Float16* As = (_Float16*)smem;
  _Float16* Bs = (_Float16*)(smem + 16384);

  const int w = tid >> 6, lane = tid & 63;
  const int quad = lane >> 4, l16 = lane & 15;
  const int dr = lane >> 4, ds = lane & 15;

  size_t a_goff[4], b_goff[4];
  int lds_off[4];
#pragma unroll
  for (int i = 0; i < 4; ++i) {
    int lrow = w * 16 + i * 4 + dr;
    int sg = ds ^ (i * 4 + dr);
    a_goff[i] = (size_t)(Mbase + lrow) * (HID * 2) + (size_t)sg * 16;
    b_goff[i] = (size_t)(nb * BN + lrow) * ((size_t)Kdim * 2) + (size_t)sg * 16;
    lds_off[i] = lrow * 256 + ds * 16;
  }

  f32x4 acc[4] = {};

  for (int kk = 0; kk < Kdim; kk += 128) {
    const char* Abase = (kk < 1024)
        ? ((const char*)A1 + (size_t)kk * 2)
        : ((const char*)A2 + (size_t)(kk - 1024) * 2);
    const char* Bbase = (const char*)Bm + (size_t)kk * 2;
#pragma unroll
    for (int i = 0; i < 4; ++i) {
      async_cp16(Abase + a_goff[i], smem + lds_off[i]);
      async_cp16(Bbase + b_goff[i], smem + 16384 + lds_off[i]);
    }
    __syncthreads();
#pragma unroll
    for (int ks = 0; ks < 4; ++ks) {
      int segq = (ks * 4 + quad) ^ l16;
      f16x8 bf = *reinterpret_cast<const f16x8*>(Bs + (w * 16 + l16) * 128 + segq * 8);
#pragma unroll
      for (int mt = 0; mt < 4; ++mt) {
        f16x8 af = *reinterpret_cast<const f16x8*>(As + (mt * 16 + l16) * 128 + segq * 8);
        acc[mt] = __builtin_amdgcn_mfma_f32_16x16x32_f16(af, bf, acc[mt], 0, 0, 0);
      }
    }
    __syncthreads();
  }

  float* Gs = (float*)smem;
#pragma unroll
  for (int mt = 0; mt < 4; ++mt) {
    int row = mt * 16 + quad * 4;
    int col = w * 16 + l16;
#pragma unroll
    for (int r = 0; r < 4; ++r)
      Gs[(row + r) * GSTR + col] = acc[mt][r];
  }
  __syncthreads();

#pragma unroll
  for (int i = 0; i < 4; ++i) {
    int m = (tid >> 4) + i * 16;
    int u = tid & 15;
    float gi = Gs[m * GSTR + u];
    float gf = Gs[m * GSTR + 16 + u];
    float gg = Gs[m * GSTR + 32 + u];
    float go = Gs[m * GSTR + 48 + u];
    int nbase = nb * BN;
    gi += bias[nbase + u];
    gf += bias[nbase + 16 + u];
    gg += bias[nbase + 32 + u];
    go += bias[nbase + 48 + u];
    if (layer == 0) {
#pragma unroll
      for (int k = 0; k < SK; ++k) {
        float sv = SmallIn[m * SK + k];
        gi += sv * W0s[u * 11 + k];
        gf += sv * W0s[(16 + u) * 11 + k];
        gg += sv * W0s[(32 + u) * 11 + k];
        go += sv * W0s[(48 + u) * 11 + k];
      }
    }
    size_t cidx = (size_t)(Mbase + m) * HID + (size_t)nb * 16 + u;
    float cold = cst[cidx];
    float cn = sigmoidf_fast(gf) * cold + sigmoidf_fast(gi) * tanhf_fast(gg);
    float hn = sigmoidf_fast(go) * tanhf_fast(cn);
    cst[cidx] = cn;
    ho[cidx] = (_Float16)hn;
  }
}

// ---------------------------------------------------------------------------
// Persistent-decoder layer body. BK=128 chunks, 3x32KB LDS bufs, depth-2,
// fine-grained vmcnt. MODE 1: L0 (+small input). MODE 2: deep. MODE 3: deep
// + fused fc -> atomicAdd out[:, s+1, :].
// ---------------------------------------------------------------------------
template<int KC, int MODE>
__device__ __forceinline__ void dec_layer(
    const char* A1, const char* A2, const char* Bm,
    const int* a_off, const int* b_off, const int* l_off,
    char* smem, float* Gs, const float* SmallIn, const float* W0s,
    const float* biasg, float* creg, _Float16* hout, float* out,
    const float* w7, const float* fcadd, int s, int Mbase, int nb, int tid)
{
  const int w = tid >> 6, lane = tid & 63;
  const int quad = lane >> 4, l16 = lane & 15;
  f32x4 acc[4] = {};

#define DISSUE(c) do { \
    const char* Ab_ = (KC == 8 || (c) < 8) ? (A1 + (size_t)(c) * 256) \
                                           : (A2 + (size_t)((c) - 8) * 256); \
    const char* Bb_ = Bm + (size_t)(c) * 256; \
    char* Lb_ = smem + ((c) % 3) * 32768; \
    _Pragma("unroll") \
    for (int i_ = 0; i_ < 4; ++i_) { \
      async_cp16(Ab_ + a_off[i_], Lb_ + l_off[i_]); \
      async_cp16(Bb_ + b_off[i_], Lb_ + 16384 + l_off[i_]); \
    } } while (0)

  DISSUE(0);
  DISSUE(1);
#pragma unroll
  for (int c = 0; c < KC; ++c) {
    if (c + 2 < KC)       { DISSUE(c + 2); WBAR(16); }
    else if (c + 2 == KC) { WBAR(8); }
    else                  { WBAR(0); }
    const _Float16* As = (const _Float16*)(smem + (c % 3) * 32768);
    const _Float16* Bs = As + 8192;
#pragma unroll
    for (int ks = 0; ks < 4; ++ks) {
      int sq = (ks * 4 + quad) ^ l16;
      f16x8 bf = *reinterpret_cast<const f16x8*>(Bs + (w * 16 + l16) * 128 + sq * 8);
#pragma unroll
      for (int mt = 0; mt < 4; ++mt) {
        f16x8 af = *reinterpret_cast<const f16x8*>(As + (mt * 16 + l16) * 128 + sq * 8);
        acc[mt] = __builtin_amdgcn_mfma_f32_16x16x32_f16(af, bf, acc[mt], 0, 0, 0);
      }
    }
    BARO();   // buffer-recycle guard
  }
#undef DISSUE

#pragma unroll
  for (int mt = 0; mt < 4; ++mt) {
    int row = mt * 16 + quad * 4;
    int col = w * 16 + l16;
#pragma unroll
    for (int r = 0; r < 4; ++r)
      Gs[(row + r) * GSTR + col] = acc[mt][r];
  }
  __syncthreads();

#pragma unroll
  for (int i = 0; i < 4; ++i) {
    int m = (tid >> 4) + i * 16;
    int u = tid & 15;
    float gi = Gs[m * GSTR + u]      + biasg[0];
    float gf = Gs[m * GSTR + 16 + u] + biasg[1];
    float gg = Gs[m * GSTR + 32 + u] + biasg[2];
    float go = Gs[m * GSTR + 48 + u] + biasg[3];
    if (MODE == 1) {
#pragma unroll
      for (int k = 0; k < SK; ++k) {
        float sv = SmallIn[m * SK + k];
        gi += sv * W0s[u * 11 + k];
        gf += sv * W0s[(16 + u) * 11 + k];
        gg += sv * W0s[(32 + u) * 11 + k];
        go += sv * W0s[(48 + u) * 11 + k];
      }
    }
    float cn = sigmoidf_fast(gf) * creg[i] + sigmoidf_fast(gi) * tanhf_fast(gg);
    float hn = sigmoidf_fast(go) * tanhf_fast(cn);
    creg[i] = cn;
    hout[(size_t)(Mbase + m) * HID + (size_t)nb * 16 + u] = (_Float16)hn;
    if (MODE == 3) {
#pragma unroll
      for (int o = 0; o < OUTD; ++o) {
        float r = hn * w7[o];
        r += __shfl_xor(r, 1, 16);
        r += __shfl_xor(r, 2, 16);
        r += __shfl_xor(r, 4, 16);
        r += __shfl_xor(r, 8, 16);
        if (u == 0)
          atomicAdd(&out[(size_t)(Mbase + m) * (PRED * OUTD) + (s + 1) * OUTD + o],
                    r + fcadd[o]);
      }
    }
  }
}

// ---------------------------------------------------------------------------
// Persistent decoder: ONE kernel runs all 95 steps x 3 layers with
// device-wide barriers. Grid 256 blocks (nb = id&63 -> XCD-stable),
// LDS 121KB -> 1 block/CU -> all blocks co-resident (manual barrier safe).
// c-state, bias, fcW slice live in registers across all steps.
// ---------------------------------------------------------------------------
__global__ __launch_bounds__(256, 1) void lstm_dec(
    _Float16* __restrict__ h0a, _Float16* __restrict__ h0b,
    _Float16* __restrict__ h1a, _Float16* __restrict__ h1b,
    _Float16* __restrict__ h2a, _Float16* __restrict__ h2b,
    const _Float16* __restrict__ B0g, const _Float16* __restrict__ B1g,
    const _Float16* __restrict__ B2g,
    const float* __restrict__ biasP, const float* __restrict__ W0p,
    const float* __restrict__ cbuf,
    float* __restrict__ out, const int* __restrict__ yte,
    const float* __restrict__ e0, const float* __restrict__ e1,
    const float* __restrict__ e2, const float* __restrict__ e3,
    const float* __restrict__ fcW, const float* __restrict__ fcb,
    unsigned* __restrict__ bar)
{
  __shared__ __align__(16) char smem[3 * 32768];   // 96 KB staging
  __shared__ float Gs[BM * GSTR];                  // 17 KB
  __shared__ float SmallIn[BM * SK];
  __shared__ float W0s[BN * 11];

  const int tid = threadIdx.x;
  const int nb = blockIdx.x & 63, mb = blockIdx.x >> 6;
  const int Mbase = mb * BM;
  const int w = tid >> 6, lane = tid & 63;
  const int dr = lane >> 4, ds = lane & 15;

  int a_off[4], b1_off[4], b2_off[4], l_off[4];
#pragma unroll
  for (int i = 0; i < 4; ++i) {
    int lrow = w * 16 + i * 4 + dr;
    int sg = ds ^ (i * 4 + dr);
    a_off[i]  = (Mbase + lrow) * 2048 + sg * 16;
    b1_off[i] = (nb * 64 + lrow) * 2048 + sg * 16;
    b2_off[i] = (nb * 64 + lrow) * 4096 + sg * 16;
    l_off[i]  = lrow * 256 + ds * 16;
  }

  if (tid < BN) {
    const float* wp = W0p + (size_t)(nb * BN + tid) * SK;
#pragma unroll
    for (int i = 0; i < SK; ++i) W0s[tid * 11 + i] = wp[i];
  }

  const int u = tid & 15;
  float biasr[3][4];
#pragma unroll
  for (int l = 0; l < 3; ++l)
#pragma unroll
    for (int g = 0; g < 4; ++g)
      biasr[l][g] = biasP[l * 4096 + nb * 64 + g * 16 + u];

  float creg[3][4];
#pragma unroll
  for (int l = 0; l < 3; ++l)
#pragma unroll
    for (int i = 0; i < 4; ++i) {
      int m = (tid >> 4) + i * 16;
      creg[l][i] = cbuf[(size_t)l * 262144 + (size_t)(Mbase + m) * HID + nb * 16 + u];
    }

  float w7[OUTD], fcadd[OUTD];
#pragma unroll
  for (int o = 0; o < OUTD; ++o) {
    w7[o] = fcW[(size_t)o * HID + nb * 16 + u];
    fcadd[o] = (nb == 0) ? fcb[o] : 0.0f;
  }

  _Float16* h0[2] = {h0a, h0b};
  _Float16* h1[2] = {h1a, h1b};
  _Float16* h2[2] = {h2a, h2b};
  int p0 = 0, p1 = 1, p2 = 0;   // encoder handoff parities
  unsigned bc = 0;

  for (int s = 0; s < PRED - 1; ++s) {
    // small input for L0 (reads y_s from out, written by prev step / fc_kernel)
    if (tid < BM) {
      int Mg = Mbase + tid;
      float v[SK];
      const float* yp = out + (size_t)Mg * (PRED * OUTD) + s * OUTD;
#pragma unroll
      for (int i = 0; i < OUTD; ++i) v[i] = yp[i];
      const int* ip = yte + ((size_t)Mg * PRED + s) * 4;
      int i0 = ip[0], i1 = ip[1], i2 = ip[2], i3 = ip[3];
#pragma unroll
      for (int dd = 0; dd < 3; ++dd)
        v[IND + dd] = e0[i0 * 3 + dd] + e1[i1 * 3 + dd] + e2[i2 * 3 + dd] + e3[i3 * 3 + dd];
#pragma unroll
      for (int i = 0; i < SK; ++i) SmallIn[tid * SK + i] = v[i];
    }

    dec_layer<8, 1>((const char*)h0[p0], (const char*)h0[p0], (const char*)B0g,
                    a_off, b1_off, l_off, smem, Gs, SmallIn, W0s,
                    biasr[0], creg[0], h0[1 - p0], out, w7, fcadd, s, Mbase, nb, tid);
    gridbar(bar, ++bc * 256);

    dec_layer<16, 2>((const char*)h0[1 - p0], (const char*)h1[p1], (const char*)B1g,
                     a_off, b2_off, l_off, smem, Gs, SmallIn, W0s,
                     biasr[1], creg[1], h1[1 - p1], out, w7, fcadd, s, Mbase, nb, tid);
    gridbar(bar, ++bc * 256);

    dec_layer<16, 3>((const char*)h1[1 - p1], (const char*)h2[p2], (const char*)B2g,
                     a_off, b2_off, l_off, smem, Gs, SmallIn, W0s,
                     biasr[2], creg[2], h2[1 - p2], out, w7, fcadd, s, Mbase, nb, tid);
    gridbar(bar, ++bc * 256);

    p0 ^= 1; p1 ^= 1; p2 ^= 1;
  }
}

// ---------------------------------------------------------------------------
// Standalone FC head for y0 only: y = h2 @ fcW^T + fcb -> out[:,0,:].
// ---------------------------------------------------------------------------
__global__ __launch_bounds__(256) void fc_kernel(
    const _Float16* __restrict__ h2, const float* __restrict__ fcW,
    const float* __restrict__ fcb, float* __restrict__ out)
{
  int wv = threadIdx.x >> 6, lane = threadIdx.x & 63;
  int row = blockIdx.x * 4 + wv;
  const _Float16* hp = h2 + (size_t)row * HID + lane * 16;
  float hv[16];
#pragma unroll
  for (int i = 0; i < 16; ++i) hv[i] = (float)hp[i];
  float acc[OUTD];
#pragma unroll
  for (int o = 0; o < OUTD; ++o) {
    const float* wp = fcW + (size_t)o * HID + lane * 16;
    float a = 0.f;
#pragma unroll
    for (int i = 0; i < 16; ++i) a += hv[i] * wp[i];
    acc[o] = a;
  }
#pragma unroll
  for (int o = 0; o < OUTD; ++o)
#pragma unroll
    for (int off = 32; off >= 1; off >>= 1)
      acc[o] += __shfl_xor(acc[o], off, 64);
  if (lane == 0) {
#pragma unroll
    for (int o = 0; o < OUTD; ++o)
      out[(size_t)row * (PRED * OUTD) + o] = acc[o] + fcb[o];
  }
}

// ---------------------------------------------------------------------------
// Workspace layout (bytes):
//   B0 @0 (8 MB) | B1 @8388608 (16 MB) | B2 @25165824 (16 MB)
//   W0p @41943040 | biasP @42106880
//   h par0 @42156032 (1.5 MB) + c @43728896 (3 MB)  } one memset
//   h par1 @46874624 (1.5 MB)                        } second memset
//   bar @48447488 (4 B)
// ---------------------------------------------------------------------------
extern "C" void kernel_launch(void* const* d_in, const int* in_sizes, int n_in,
                              void* d_out, int out_size, void* d_ws, size_t ws_size,
                              hipStream_t stream) {
  const float* x   = (const float*)d_in[0];
  const int*   xte = (const int*)d_in[2];
  const int*   yte = (const int*)d_in[3];
  const float* e0  = (const float*)d_in[4];
  const float* e1  = (const float*)d_in[5];
  const float* e2  = (const float*)d_in[6];
  const float* e3  = (const float*)d_in[7];
  const float* Wih0 = (const float*)d_in[8];
  const float* Whh0 = (const float*)d_in[9];
  const float* bih0 = (const float*)d_in[10];
  const float* bhh0 = (const float*)d_in[11];
  const float* Wih1 = (const float*)d_in[12];
  const float* Whh1 = (const float*)d_in[13];
  const float* bih1 = (const float*)d_in[14];
  const float* bhh1 = (const float*)d_in[15];
  const float* Wih2 = (const float*)d_in[16];
  const float* Whh2 = (const float*)d_in[17];
  const float* bih2 = (const float*)d_in[18];
  const float* bhh2 = (const float*)d_in[19];
  const float* fcW = (const float*)d_in[20];
  const float* fcb = (const float*)d_in[21];
  float* out = (float*)d_out;

  char* ws = (char*)d_ws;
  _Float16* B0   = (_Float16*)(ws);
  _Float16* B1   = (_Float16*)(ws + 8388608);
  _Float16* B2   = (_Float16*)(ws + 25165824);
  float*    W0p  = (float*)(ws + 41943040);
  float*    biasP= (float*)(ws + 42106880);
  char*     hp0  = ws + 42156032;
  float*    cbuf = (float*)(ws + 43728896);
  char*     hp1  = ws + 46874624;
  unsigned* bar  = (unsigned*)(ws + 48447488);

  hipMemsetAsync(out, 0, (size_t)out_size * 4, stream);
  hipMemsetAsync(hp0, 0, 4718592, stream);
  hipMemsetAsync(hp1, 0, 1572864, stream);
  hipMemsetAsync(bar, 0, 4, stream);

  prep_kernel<<<82128, 256, 0, stream>>>(Wih0, Whh0, bih0, bhh0,
                                         Wih1, Whh1, bih1, bhh1,
                                         Wih2, Whh2, bih2, bhh2,
                                         B0, B1, B2, W0p, biasP);

  auto hb = [&](int l, int par) -> _Float16* {
    return (_Float16*)((par ? hp1 : hp0) + (size_t)l * 524288);
  };
  float* cl[3] = {cbuf, cbuf + 262144, cbuf + 524288};

  // encoder: wavefront over (layer, t) diagonals
  for (int d = 0; d < TSEQ + 2; ++d) {
    lstm_wave<<<dim3(64, 12), 256, 0, stream>>>(
        d, hb(0,0), hb(0,1), hb(1,0), hb(1,1), hb(2,0), hb(2,1),
        B0, B1, B2, biasP, W0p, cl[0], cl[1], cl[2],
        x, xte, e0, e1, e2, e3);
  }

  // handoff parities: h0@127 -> par0, h1@127 -> par1, h2@127 -> par0
  fc_kernel<<<64, 256, 0, stream>>>(hb(2,0), fcW, fcb, out);   // y0

  lstm_dec<<<256, 256, 0, stream>>>(
      hb(0,0), hb(0,1), hb(1,0), hb(1,1), hb(2,0), hb(2,1),
      B0, B1, B2, biasP, W0p, cbuf,
      out, yte, e0, e1, e2, e3, fcW, fcb, bar);
}

// Round 6
// 19591.827 us; speedup vs baseline: 1.0747x; 1.0042x over previous
//
#include <hip/hip_runtime.h>

#define HID   1024
#define BATCH 256
#define TSEQ  128
#define PRED  96
#define IND   7
#define OUTD  7
#define SK    10   // small input dim: 7 features + 3 time-encode dims

typedef __attribute__((ext_vector_type(8))) _Float16 f16x8;
typedef __attribute__((ext_vector_type(4))) float    f32x4;

#define BM   64
#define BN   64
#define GSTR 68    // gates LDS stride (floats), <=2-way bank aliasing (free)

__device__ __forceinline__ float sigmoidf_fast(float x) {
  return 1.0f / (1.0f + __expf(-x));
}
__device__ __forceinline__ float tanhf_fast(float x) {
  float ax = fabsf(x);
  float e  = __expf(-2.0f * ax);
  float r  = (1.0f - e) / (1.0f + e);
  return copysignf(r, x);
}

__device__ __forceinline__ void async_cp16(const void* g, void* l) {
  __builtin_amdgcn_global_load_lds(
      (const __attribute__((address_space(1))) void*)g,
      (__attribute__((address_space(3))) void*)l, 16, 0, 0);
}

// fine-grained wait + barrier (pipeline): NEVER vmcnt(0) mid-loop
#define WBAR(N) asm volatile("s_waitcnt vmcnt(" #N ")\n\ts_barrier" ::: "memory")
#define BARO()  asm volatile("s_barrier" ::: "memory")

// Device-wide barrier. History:
//  R4: ACQUIRE-scope poll -> one buffer_inv (L2 invalidate) PER POLL -> 17.4ms.
//  R5: RELAXED agent poll -> load served from the local NON-COHERENT XCD L2 ->
//      spins on a STALE copy of bar until the line is randomly evicted
//      (~50us/barrier) -> 16.3ms.
//  Fix: SYSTEM-scope relaxed load -> global_load sc0 sc1, bypasses L1/L2,
//  reads the coherence point every poll, no cache maintenance side effects.
// Safe: 256 blocks, >120KB LDS -> 1 block/CU -> all co-resident.
__device__ __forceinline__ void gridbar(unsigned* bar, unsigned tgt) {
  __threadfence();                 // release: publish h/c/out stores
  __syncthreads();
  if (threadIdx.x == 0) {
    __hip_atomic_fetch_add(bar, 1u, __ATOMIC_RELAXED, __HIP_MEMORY_SCOPE_AGENT);
    while (__hip_atomic_load(bar, __ATOMIC_RELAXED, __HIP_MEMORY_SCOPE_SYSTEM) < tgt)
      __builtin_amdgcn_s_sleep(4);
  }
  __syncthreads();
  __threadfence();                 // acquire: one L2 inv per block per barrier
}

// ---------------------------------------------------------------------------
// Weight prep: fp16 B [n][k], n = nb*64 + gate*16 + u <-> r = gate*1024+nb*16+u
// ---------------------------------------------------------------------------
__global__ __launch_bounds__(256) void prep_kernel(
    const float* __restrict__ Wih0, const float* __restrict__ Whh0,
    const float* __restrict__ bih0, const float* __restrict__ bhh0,
    const float* __restrict__ Wih1, const float* __restrict__ Whh1,
    const float* __restrict__ bih1, const float* __restrict__ bhh1,
    const float* __restrict__ Wih2, const float* __restrict__ Whh2,
    const float* __restrict__ bih2, const float* __restrict__ bhh2,
    _Float16* __restrict__ B0, _Float16* __restrict__ B1, _Float16* __restrict__ B2,
    float* __restrict__ W0p, float* __restrict__ biasP)
{
  size_t e = (size_t)blockIdx.x * 256 + threadIdx.x;
  const size_t S0 = (size_t)4096 * 1024;
  const size_t S1 = (size_t)4096 * 2048;
  if (e < S0) {
    int n = (int)(e >> 10), k = (int)(e & 1023);
    int nb = n >> 6, gate = (n >> 4) & 3, u = n & 15;
    int r = gate * 1024 + nb * 16 + u;
    B0[e] = (_Float16)Whh0[(size_t)r * 1024 + k];
  } else if (e < S0 + S1) {
    size_t q = e - S0;
    int n = (int)(q >> 11), k = (int)(q & 2047);
    int nb = n >> 6, gate = (n >> 4) & 3, u = n & 15;
    int r = gate * 1024 + nb * 16 + u;
    float v = (k < 1024) ? Wih1[(size_t)r * 1024 + k]
                         : Whh1[(size_t)r * 1024 + (k - 1024)];
    B1[q] = (_Float16)v;
  } else if (e < S0 + 2 * S1) {
    size_t q = e - S0 - S1;
    int n = (int)(q >> 11), k = (int)(q & 2047);
    int nb = n >> 6, gate = (n >> 4) & 3, u = n & 15;
    int r = gate * 1024 + nb * 16 + u;
    float v = (k < 1024) ? Wih2[(size_t)r * 1024 + k]
                         : Whh2[(size_t)r * 1024 + (k - 1024)];
    B2[q] = (_Float16)v;
  } else if (e < S0 + 2 * S1 + 40960) {
    int q = (int)(e - S0 - 2 * S1);
    int n = q / 10, k = q - n * 10;
    int nb = n >> 6, gate = (n >> 4) & 3, u = n & 15;
    int r = gate * 1024 + nb * 16 + u;
    W0p[q] = Wih0[(size_t)r * 10 + k];
  } else if (e < S0 + 2 * S1 + 40960 + 12288) {
    int q = (int)(e - S0 - 2 * S1 - 40960);
    int l = q >> 12, n = q & 4095;
    int nb = n >> 6, gate = (n >> 4) & 3, u = n & 15;
    int r = gate * 1024 + nb * 16 + u;
    const float* bi = (l == 0) ? bih0 : (l == 1) ? bih1 : bih2;
    const float* bh = (l == 0) ? bhh0 : (l == 1) ? bhh1 : bhh2;
    biasP[q] = bi[r] + bh[r];
  }
}

// ---------------------------------------------------------------------------
// Encoder wavefront kernel: dispatch d computes L0@t=d, L1@t=d-1, L2@t=d-2.
// Grid (64, 12), 3 blocks/CU.
// ---------------------------------------------------------------------------
__global__ __launch_bounds__(256) void lstm_wave(
    int d,
    _Float16* __restrict__ h0p0, _Float16* __restrict__ h0p1,
    _Float16* __restrict__ h1p0, _Float16* __restrict__ h1p1,
    _Float16* __restrict__ h2p0, _Float16* __restrict__ h2p1,
    const _Float16* __restrict__ B0g, const _Float16* __restrict__ B1g,
    const _Float16* __restrict__ B2g,
    const float* __restrict__ biasP, const float* __restrict__ W0p,
    float* __restrict__ c0, float* __restrict__ c1, float* __restrict__ c2,
    const float* __restrict__ x, const int* __restrict__ xte,
    const float* __restrict__ e0, const float* __restrict__ e1,
    const float* __restrict__ e2, const float* __restrict__ e3)
{
  __shared__ __align__(16) char smem[32768];
  __shared__ float SmallIn[BM * SK];
  __shared__ float W0s[BN * 11];

  const int layer = blockIdx.y >> 2;
  const int mb = blockIdx.y & 3, nb = blockIdx.x;
  const int t = d - layer;
  if (t < 0 || t >= TSEQ) return;
  const int p = d & 1;

  const _Float16 *A1, *A2; _Float16* ho; const _Float16* Bm;
  const float* bias; float* cst; int Kdim;
  if (layer == 0) {
    A1 = p ? h0p1 : h0p0; A2 = A1;              ho = p ? h0p0 : h0p1;
    Bm = B0g; bias = biasP;        cst = c0; Kdim = 1024;
  } else if (layer == 1) {
    A1 = p ? h0p1 : h0p0; A2 = p ? h1p1 : h1p0; ho = p ? h1p0 : h1p1;
    Bm = B1g; bias = biasP + 4096; cst = c1; Kdim = 2048;
  } else {
    A1 = p ? h1p1 : h1p0; A2 = p ? h2p1 : h2p0; ho = p ? h2p0 : h2p1;
    Bm = B2g; bias = biasP + 8192; cst = c2; Kdim = 2048;
  }
  const int Mbase = mb * BM;
  const int tid = threadIdx.x;

  if (layer == 0 && tid < BM) {
    int Mg = Mbase + tid;
    float v[SK];
    const float* xp = x + ((size_t)Mg * TSEQ + t) * IND;
#pragma unroll
    for (int i = 0; i < IND; ++i) v[i] = xp[i];
    const int* ip = xte + ((size_t)Mg * TSEQ + t) * 4;
    int i0 = ip[0], i1 = ip[1], i2 = ip[2], i3 = ip[3];
#pragma unroll
    for (int dd = 0; dd < 3; ++dd)
      v[IND + dd] = e0[i0 * 3 + dd] + e1[i1 * 3 + dd] + e2[i2 * 3 + dd] + e3[i3 * 3 + dd];
#pragma unroll
    for (int i = 0; i < SK; ++i) SmallIn[tid * SK + i] = v[i];
    const float* wp = W0p + (size_t)(nb * BN + tid) * SK;
#pragma unroll
    for (int i = 0; i < SK; ++i) W0s[tid * 11 + i] = wp[i];
  }

  _Float16* As = (_Float16*)smem;
  _Float16* Bs = (_Float16*)(smem + 16384);

  const int w = tid >> 6, lane = tid & 63;
  const int quad = lane >> 4, l16 = lane & 15;
  const int dr = lane >> 4, ds = lane & 15;

  size_t a_goff[4], b_goff[4];
  int lds_off[4];
#pragma unroll
  for (int i = 0; i < 4; ++i) {
    int lrow = w * 16 + i * 4 + dr;
    int sg = ds ^ (i * 4 + dr);
    a_goff[i] = (size_t)(Mbase + lrow) * (HID * 2) + (size_t)sg * 16;
    b_goff[i] = (size_t)(nb * BN + lrow) * ((size_t)Kdim * 2) + (size_t)sg * 16;
    lds_off[i] = lrow * 256 + ds * 16;
  }

  f32x4 acc[4] = {};

  for (int kk = 0; kk < Kdim; kk += 128) {
    const char* Abase = (kk < 1024)
        ? ((const char*)A1 + (size_t)kk * 2)
        : ((const char*)A2 + (size_t)(kk - 1024) * 2);
    const char* Bbase = (const char*)Bm + (size_t)kk * 2;
#pragma unroll
    for (int i = 0; i < 4; ++i) {
      async_cp16(Abase + a_goff[i], smem + lds_off[i]);
      async_cp16(Bbase + b_goff[i], smem + 16384 + lds_off[i]);
    }
    __syncthreads();
#pragma unroll
    for (int ks = 0; ks < 4; ++ks) {
      int segq = (ks * 4 + quad) ^ l16;
      f16x8 bf = *reinterpret_cast<const f16x8*>(Bs + (w * 16 + l16) * 128 + segq * 8);
#pragma unroll
      for (int mt = 0; mt < 4; ++mt) {
        f16x8 af = *reinterpret_cast<const f16x8*>(As + (mt * 16 + l16) * 128 + segq * 8);
        acc[mt] = __builtin_amdgcn_mfma_f32_16x16x32_f16(af, bf, acc[mt], 0, 0, 0);
      }
    }
    __syncthreads();
  }

  float* Gs = (float*)smem;
#pragma unroll
  for (int mt = 0; mt < 4; ++mt) {
    int row = mt * 16 + quad * 4;
    int col = w * 16 + l16;
#pragma unroll
    for (int r = 0; r < 4; ++r)
      Gs[(row + r) * GSTR + col] = acc[mt][r];
  }
  __syncthreads();

#pragma unroll
  for (int i = 0; i < 4; ++i) {
    int m = (tid >> 4) + i * 16;
    int u = tid & 15;
    float gi = Gs[m * GSTR + u];
    float gf = Gs[m * GSTR + 16 + u];
    float gg = Gs[m * GSTR + 32 + u];
    float go = Gs[m * GSTR + 48 + u];
    int nbase = nb * BN;
    gi += bias[nbase + u];
    gf += bias[nbase + 16 + u];
    gg += bias[nbase + 32 + u];
    go += bias[nbase + 48 + u];
    if (layer == 0) {
#pragma unroll
      for (int k = 0; k < SK; ++k) {
        float sv = SmallIn[m * SK + k];
        gi += sv * W0s[u * 11 + k];
        gf += sv * W0s[(16 + u) * 11 + k];
        gg += sv * W0s[(32 + u) * 11 + k];
        go += sv * W0s[(48 + u) * 11 + k];
      }
    }
    size_t cidx = (size_t)(Mbase + m) * HID + (size_t)nb * 16 + u;
    float cold = cst[cidx];
    float cn = sigmoidf_fast(gf) * cold + sigmoidf_fast(gi) * tanhf_fast(gg);
    float hn = sigmoidf_fast(go) * tanhf_fast(cn);
    cst[cidx] = cn;
    ho[cidx] = (_Float16)hn;
  }
}

// ---------------------------------------------------------------------------
// Persistent-decoder layer body. BK=128 chunks, 4x32KB LDS bufs, depth-3,
// fine-grained vmcnt. MODE 1: L0 (+small input). MODE 2: deep. MODE 3: deep
// + fused fc -> atomicAdd out[:, s+1, :].
// ---------------------------------------------------------------------------
template<int KC, int MODE>
__device__ __forceinline__ void dec_layer(
    const char* A1, const char* A2, const char* Bm,
    const int* a_off, const int* b_off, const int* l_off,
    char* smem, float* Gs, const float* SmallIn, const float* W0s,
    const float* biasg, float* creg, _Float16* hout, float* out,
    const float* w7, const float* fcadd, int s, int Mbase, int nb, int tid)
{
  const int w = tid >> 6, lane = tid & 63;
  const int quad = lane >> 4, l16 = lane & 15;
  f32x4 acc[4] = {};

#define DISSUE(c) do { \
    const char* Ab_ = (KC == 8 || (c) < 8) ? (A1 + (size_t)(c) * 256) \
                                           : (A2 + (size_t)((c) - 8) * 256); \
    const char* Bb_ = Bm + (size_t)(c) * 256; \
    char* Lb_ = smem + ((c) % 4) * 32768; \
    _Pragma("unroll") \
    for (int i_ = 0; i_ < 4; ++i_) { \
      async_cp16(Ab_ + a_off[i_], Lb_ + l_off[i_]); \
      async_cp16(Bb_ + b_off[i_], Lb_ + 16384 + l_off[i_]); \
    } } while (0)

  DISSUE(0);
  DISSUE(1);
  DISSUE(2);
#pragma unroll
  for (int c = 0; c < KC; ++c) {
    if (c + 3 < KC)       { DISSUE(c + 3); WBAR(24); }
    else if (c + 3 == KC) { WBAR(16); }
    else if (c + 2 == KC) { WBAR(8); }
    else                  { WBAR(0); }
    const _Float16* As = (const _Float16*)(smem + (c % 4) * 32768);
    const _Float16* Bs = As + 8192;
#pragma unroll
    for (int ks = 0; ks < 4; ++ks) {
      int sq = (ks * 4 + quad) ^ l16;
      f16x8 bf = *reinterpret_cast<const f16x8*>(Bs + (w * 16 + l16) * 128 + sq * 8);
#pragma unroll
      for (int mt = 0; mt < 4; ++mt) {
        f16x8 af = *reinterpret_cast<const f16x8*>(As + (mt * 16 + l16) * 128 + sq * 8);
        acc[mt] = __builtin_amdgcn_mfma_f32_16x16x32_f16(af, bf, acc[mt], 0, 0, 0);
      }
    }
    BARO();   // buffer-recycle guard
  }
#undef DISSUE

#pragma unroll
  for (int mt = 0; mt < 4; ++mt) {
    int row = mt * 16 + quad * 4;
    int col = w * 16 + l16;
#pragma unroll
    for (int r = 0; r < 4; ++r)
      Gs[(row + r) * GSTR + col] = acc[mt][r];
  }
  __syncthreads();

#pragma unroll
  for (int i = 0; i < 4; ++i) {
    int m = (tid >> 4) + i * 16;
    int u = tid & 15;
    float gi = Gs[m * GSTR + u]      + biasg[0];
    float gf = Gs[m * GSTR + 16 + u] + biasg[1];
    float gg = Gs[m * GSTR + 32 + u] + biasg[2];
    float go = Gs[m * GSTR + 48 + u] + biasg[3];
    if (MODE == 1) {
#pragma unroll
      for (int k = 0; k < SK; ++k) {
        float sv = SmallIn[m * SK + k];
        gi += sv * W0s[u * 11 + k];
        gf += sv * W0s[(16 + u) * 11 + k];
        gg += sv * W0s[(32 + u) * 11 + k];
        go += sv * W0s[(48 + u) * 11 + k];
      }
    }
    float cn = sigmoidf_fast(gf) * creg[i] + sigmoidf_fast(gi) * tanhf_fast(gg);
    float hn = sigmoidf_fast(go) * tanhf_fast(cn);
    creg[i] = cn;
    hout[(size_t)(Mbase + m) * HID + (size_t)nb * 16 + u] = (_Float16)hn;
    if (MODE == 3) {
#pragma unroll
      for (int o = 0; o < OUTD; ++o) {
        float r = hn * w7[o];
        r += __shfl_xor(r, 1, 16);
        r += __shfl_xor(r, 2, 16);
        r += __shfl_xor(r, 4, 16);
        r += __shfl_xor(r, 8, 16);
        if (u == 0)
          atomicAdd(&out[(size_t)(Mbase + m) * (PRED * OUTD) + (s + 1) * OUTD + o],
                    r + fcadd[o]);
      }
    }
  }
}

// ---------------------------------------------------------------------------
// Persistent decoder: ONE kernel runs all 95 steps x 3 layers with
// device-wide barriers. Grid 256 blocks (nb = id&63 -> XCD-stable),
// LDS ~150KB -> 1 block/CU -> all blocks co-resident (manual barrier safe).
// c-state, bias, fcW slice live in registers across all steps.
// ---------------------------------------------------------------------------
__global__ __launch_bounds__(256, 1) void lstm_dec(
    _Float16* __restrict__ h0a, _Float16* __restrict__ h0b,
    _Float16* __restrict__ h1a, _Float16* __restrict__ h1b,
    _Float16* __restrict__ h2a, _Float16* __restrict__ h2b,
    const _Float16* __restrict__ B0g, const _Float16* __restrict__ B1g,
    const _Float16* __restrict__ B2g,
    const float* __restrict__ biasP, const float* __restrict__ W0p,
    const float* __restrict__ cbuf,
    float* __restrict__ out, const int* __restrict__ yte,
    const float* __restrict__ e0, const float* __restrict__ e1,
    const float* __restrict__ e2, const float* __restrict__ e3,
    const float* __restrict__ fcW, const float* __restrict__ fcb,
    unsigned* __restrict__ bar)
{
  __shared__ __align__(16) char smem[4 * 32768];   // 128 KB staging
  __shared__ float Gs[BM * GSTR];                  // 17 KB
  __shared__ float SmallIn[BM * SK];
  __shared__ float W0s[BN * 11];

  const int tid = threadIdx.x;
  const int nb = blockIdx.x & 63, mb = blockIdx.x >> 6;
  const int Mbase = mb * BM;
  const int w = tid >> 6, lane = tid & 63;
  const int dr = lane >> 4, ds = lane & 15;

  int a_off[4], b1_off[4], b2_off[4], l_off[4];
#pragma unroll
  for (int i = 0; i < 4; ++i) {
    int lrow = w * 16 + i * 4 + dr;
    int sg = ds ^ (i * 4 + dr);
    a_off[i]  = (Mbase + lrow) * 2048 + sg * 16;
    b1_off[i] = (nb * 64 + lrow) * 2048 + sg * 16;
    b2_off[i] = (nb * 64 + lrow) * 4096 + sg * 16;
    l_off[i]  = lrow * 256 + ds * 16;
  }

  if (tid < BN) {
    const float* wp = W0p + (size_t)(nb * BN + tid) * SK;
#pragma unroll
    for (int i = 0; i < SK; ++i) W0s[tid * 11 + i] = wp[i];
  }

  const int u = tid & 15;
  float biasr[3][4];
#pragma unroll
  for (int l = 0; l < 3; ++l)
#pragma unroll
    for (int g = 0; g < 4; ++g)
      biasr[l][g] = biasP[l * 4096 + nb * 64 + g * 16 + u];

  float creg[3][4];
#pragma unroll
  for (int l = 0; l < 3; ++l)
#pragma unroll
    for (int i = 0; i < 4; ++i) {
      int m = (tid >> 4) + i * 16;
      creg[l][i] = cbuf[(size_t)l * 262144 + (size_t)(Mbase + m) * HID + nb * 16 + u];
    }

  float w7[OUTD], fcadd[OUTD];
#pragma unroll
  for (int o = 0; o < OUTD; ++o) {
    w7[o] = fcW[(size_t)o * HID + nb * 16 + u];
    fcadd[o] = (nb == 0) ? fcb[o] : 0.0f;
  }

  _Float16* h0[2] = {h0a, h0b};
  _Float16* h1[2] = {h1a, h1b};
  _Float16* h2[2] = {h2a, h2b};
  int p0 = 0, p1 = 1, p2 = 0;   // encoder handoff parities
  unsigned bc = 0;

  for (int s = 0; s < PRED - 1; ++s) {
    // small input for L0 (reads y_s from out, written by prev step / fc_kernel)
    if (tid < BM) {
      int Mg = Mbase + tid;
      float v[SK];
      const float* yp = out + (size_t)Mg * (PRED * OUTD) + s * OUTD;
#pragma unroll
      for (int i = 0; i < OUTD; ++i) v[i] = yp[i];
      const int* ip = yte + ((size_t)Mg * PRED + s) * 4;
      int i0 = ip[0], i1 = ip[1], i2 = ip[2], i3 = ip[3];
#pragma unroll
      for (int dd = 0; dd < 3; ++dd)
        v[IND + dd] = e0[i0 * 3 + dd] + e1[i1 * 3 + dd] + e2[i2 * 3 + dd] + e3[i3 * 3 + dd];
#pragma unroll
      for (int i = 0; i < SK; ++i) SmallIn[tid * SK + i] = v[i];
    }

    dec_layer<8, 1>((const char*)h0[p0], (const char*)h0[p0], (const char*)B0g,
                    a_off, b1_off, l_off, smem, Gs, SmallIn, W0s,
                    biasr[0], creg[0], h0[1 - p0], out, w7, fcadd, s, Mbase, nb, tid);
    gridbar(bar, ++bc * 256);

    dec_layer<16, 2>((const char*)h0[1 - p0], (const char*)h1[p1], (const char*)B1g,
                     a_off, b2_off, l_off, smem, Gs, SmallIn, W0s,
                     biasr[1], creg[1], h1[1 - p1], out, w7, fcadd, s, Mbase, nb, tid);
    gridbar(bar, ++bc * 256);

    dec_layer<16, 3>((const char*)h1[1 - p1], (const char*)h2[p2], (const char*)B2g,
                     a_off, b2_off, l_off, smem, Gs, SmallIn, W0s,
                     biasr[2], creg[2], h2[1 - p2], out, w7, fcadd, s, Mbase, nb, tid);
    gridbar(bar, ++bc * 256);

    p0 ^= 1; p1 ^= 1; p2 ^= 1;
  }
}

// ---------------------------------------------------------------------------
// Standalone FC head for y0 only: y = h2 @ fcW^T + fcb -> out[:,0,:].
// ---------------------------------------------------------------------------
__global__ __launch_bounds__(256) void fc_kernel(
    const _Float16* __restrict__ h2, const float* __restrict__ fcW,
    const float* __restrict__ fcb, float* __restrict__ out)
{
  int wv = threadIdx.x >> 6, lane = threadIdx.x & 63;
  int row = blockIdx.x * 4 + wv;
  const _Float16* hp = h2 + (size_t)row * HID + lane * 16;
  float hv[16];
#pragma unroll
  for (int i = 0; i < 16; ++i) hv[i] = (float)hp[i];
  float acc[OUTD];
#pragma unroll
  for (int o = 0; o < OUTD; ++o) {
    const float* wp = fcW + (size_t)o * HID + lane * 16;
    float a = 0.f;
#pragma unroll
    for (int i = 0; i < 16; ++i) a += hv[i] * wp[i];
    acc[o] = a;
  }
#pragma unroll
  for (int o = 0; o < OUTD; ++o)
#pragma unroll
    for (int off = 32; off >= 1; off >>= 1)
      acc[o] += __shfl_xor(acc[o], off, 64);
  if (lane == 0) {
#pragma unroll
    for (int o = 0; o < OUTD; ++o)
      out[(size_t)row * (PRED * OUTD) + o] = acc[o] + fcb[o];
  }
}

// ---------------------------------------------------------------------------
// Workspace layout (bytes):
//   B0 @0 (8 MB) | B1 @8388608 (16 MB) | B2 @25165824 (16 MB)
//   W0p @41943040 | biasP @42106880
//   h par0 @42156032 (1.5 MB) + c @43728896 (3 MB)  } one memset
//   h par1 @46874624 (1.5 MB)                        } second memset
//   bar @48447488 (4 B)
// ---------------------------------------------------------------------------
extern "C" void kernel_launch(void* const* d_in, const int* in_sizes, int n_in,
                              void* d_out, int out_size, void* d_ws, size_t ws_size,
                              hipStream_t stream) {
  const float* x   = (const float*)d_in[0];
  const int*   xte = (const int*)d_in[2];
  const int*   yte = (const int*)d_in[3];
  const float* e0  = (const float*)d_in[4];
  const float* e1  = (const float*)d_in[5];
  const float* e2  = (const float*)d_in[6];
  const float* e3  = (const float*)d_in[7];
  const float* Wih0 = (const float*)d_in[8];
  const float* Whh0 = (const float*)d_in[9];
  const float* bih0 = (const float*)d_in[10];
  const float* bhh0 = (const float*)d_in[11];
  const float* Wih1 = (const float*)d_in[12];
  const float* Whh1 = (const float*)d_in[13];
  const float* bih1 = (const float*)d_in[14];
  const float* bhh1 = (const float*)d_in[15];
  const float* Wih2 = (const float*)d_in[16];
  const float* Whh2 = (const float*)d_in[17];
  const float* bih2 = (const float*)d_in[18];
  const float* bhh2 = (const float*)d_in[19];
  const float* fcW = (const float*)d_in[20];
  const float* fcb = (const float*)d_in[21];
  float* out = (float*)d_out;

  char* ws = (char*)d_ws;
  _Float16* B0   = (_Float16*)(ws);
  _Float16* B1   = (_Float16*)(ws + 8388608);
  _Float16* B2   = (_Float16*)(ws + 25165824);
  float*    W0p  = (float*)(ws + 41943040);
  float*    biasP= (float*)(ws + 42106880);
  char*     hp0  = ws + 42156032;
  float*    cbuf = (float*)(ws + 43728896);
  char*     hp1  = ws + 46874624;
  unsigned* bar  = (unsigned*)(ws + 48447488);

  hipMemsetAsync(out, 0, (size_t)out_size * 4, stream);
  hipMemsetAsync(hp0, 0, 4718592, stream);
  hipMemsetAsync(hp1, 0, 1572864, stream);
  hipMemsetAsync(bar, 0, 4, stream);

  prep_kernel<<<82128, 256, 0, stream>>>(Wih0, Whh0, bih0, bhh0,
                                         Wih1, Whh1, bih1, bhh1,
                                         Wih2, Whh2, bih2, bhh2,
                                         B0, B1, B2, W0p, biasP);

  auto hb = [&](int l, int par) -> _Float16* {
    return (_Float16*)((par ? hp1 : hp0) + (size_t)l * 524288);
  };
  float* cl[3] = {cbuf, cbuf + 262144, cbuf + 524288};

  // encoder: wavefront over (layer, t) diagonals
  for (int d = 0; d < TSEQ + 2; ++d) {
    lstm_wave<<<dim3(64, 12), 256, 0, stream>>>(
        d, hb(0,0), hb(0,1), hb(1,0), hb(1,1), hb(2,0), hb(2,1),
        B0, B1, B2, biasP, W0p, cl[0], cl[1], cl[2],
        x, xte, e0, e1, e2, e3);
  }

  // handoff parities: h0@127 -> par0, h1@127 -> par1, h2@127 -> par0
  fc_kernel<<<64, 256, 0, stream>>>(hb(2,0), fcW, fcb, out);   // y0

  lstm_dec<<<256, 256, 0, stream>>>(
      hb(0,0), hb(0,1), hb(1,0), hb(1,1), hb(2,0), hb(2,1),
      B0, B1, B2, biasP, W0p, cbuf,
      out, yte, e0, e1, e2, e3, fcW, fcb, bar);
}

// Round 7
// 17849.248 us; speedup vs baseline: 1.1797x; 1.0976x over previous
//
#include <hip/hip_runtime.h>

#define HID   1024
#define BATCH 256
#define TSEQ  128
#define PRED  96
#define IND   7
#define OUTD  7
#define SK    10   // small input dim: 7 features + 3 time-encode dims

typedef __attribute__((ext_vector_type(8))) _Float16 f16x8;
typedef __attribute__((ext_vector_type(4))) float    f32x4;

#define BM   64
#define BN   64
#define GSTR 68    // gates LDS stride (floats), <=2-way bank aliasing (free)

__device__ __forceinline__ float sigmoidf_fast(float x) {
  return 1.0f / (1.0f + __expf(-x));
}
__device__ __forceinline__ float tanhf_fast(float x) {
  float ax = fabsf(x);
  float e  = __expf(-2.0f * ax);
  float r  = (1.0f - e) / (1.0f + e);
  return copysignf(r, x);
}

__device__ __forceinline__ void async_cp16(const void* g, void* l) {
  __builtin_amdgcn_global_load_lds(
      (const __attribute__((address_space(1))) void*)g,
      (__attribute__((address_space(3))) void*)l, 16, 0, 0);
}

// fine-grained wait + barrier (pipeline): NEVER vmcnt(0) mid-loop
#define WBAR(N) asm volatile("s_waitcnt vmcnt(" #N ")\n\ts_barrier" ::: "memory")
#define BARO()  asm volatile("s_barrier" ::: "memory")

// Device-wide barrier, v3. History:
//  R4 (acquire poll), R5 (relaxed poll), R6 (system poll): ALL ~16-17ms ->
//  poll mechanism exonerated. Invariant culprit: single fetch_add counter --
//  256 same-line atomic RMWs serialize with cross-XCD line ping-pong
//  (~200ns each -> ~50us/barrier, x285 = 14.5ms. Matches 57us/phase).
//  Fix: NO RMW. Per-block padded arrival flags (256 independent lines,
//  parallel stores), block 0 detects with 256 parallel polling threads,
//  publishes one 'go' word that everyone read-polls (no ownership transfer).
// Safe: 256 blocks, 154KB LDS -> 1 block/CU -> all co-resident.
__device__ __forceinline__ void gridbar(volatile unsigned* flags, unsigned* go,
                                        unsigned bc) {
  __threadfence();                 // release: publish h/c/out stores (wbL2)
  __syncthreads();
  const int tid = threadIdx.x;
  if (blockIdx.x == 0) {
    if (tid > 0) {                 // thread tid waits for block tid's arrival
      while (__hip_atomic_load((const unsigned*)(flags + tid * 32),
                               __ATOMIC_RELAXED, __HIP_MEMORY_SCOPE_SYSTEM) < bc)
        __builtin_amdgcn_s_sleep(1);
    }
    __syncthreads();
    if (tid == 0)
      __hip_atomic_store(go, bc, __ATOMIC_RELAXED, __HIP_MEMORY_SCOPE_SYSTEM);
  } else {
    if (tid == 0) {
      __hip_atomic_store((unsigned*)(flags + blockIdx.x * 32), bc,
                         __ATOMIC_RELAXED, __HIP_MEMORY_SCOPE_SYSTEM);
      while (__hip_atomic_load(go, __ATOMIC_RELAXED,
                               __HIP_MEMORY_SCOPE_SYSTEM) < bc)
        __builtin_amdgcn_s_sleep(1);
    }
    __syncthreads();
  }
  __threadfence();                 // acquire: invalidate L2 once per block
}

// ---------------------------------------------------------------------------
// Weight prep: fp16 B [n][k], n = nb*64 + gate*16 + u <-> r = gate*1024+nb*16+u
// ---------------------------------------------------------------------------
__global__ __launch_bounds__(256) void prep_kernel(
    const float* __restrict__ Wih0, const float* __restrict__ Whh0,
    const float* __restrict__ bih0, const float* __restrict__ bhh0,
    const float* __restrict__ Wih1, const float* __restrict__ Whh1,
    const float* __restrict__ bih1, const float* __restrict__ bhh1,
    const float* __restrict__ Wih2, const float* __restrict__ Whh2,
    const float* __restrict__ bih2, const float* __restrict__ bhh2,
    _Float16* __restrict__ B0, _Float16* __restrict__ B1, _Float16* __restrict__ B2,
    float* __restrict__ W0p, float* __restrict__ biasP)
{
  size_t e = (size_t)blockIdx.x * 256 + threadIdx.x;
  const size_t S0 = (size_t)4096 * 1024;
  const size_t S1 = (size_t)4096 * 2048;
  if (e < S0) {
    int n = (int)(e >> 10), k = (int)(e & 1023);
    int nb = n >> 6, gate = (n >> 4) & 3, u = n & 15;
    int r = gate * 1024 + nb * 16 + u;
    B0[e] = (_Float16)Whh0[(size_t)r * 1024 + k];
  } else if (e < S0 + S1) {
    size_t q = e - S0;
    int n = (int)(q >> 11), k = (int)(q & 2047);
    int nb = n >> 6, gate = (n >> 4) & 3, u = n & 15;
    int r = gate * 1024 + nb * 16 + u;
    float v = (k < 1024) ? Wih1[(size_t)r * 1024 + k]
                         : Whh1[(size_t)r * 1024 + (k - 1024)];
    B1[q] = (_Float16)v;
  } else if (e < S0 + 2 * S1) {
    size_t q = e - S0 - S1;
    int n = (int)(q >> 11), k = (int)(q & 2047);
    int nb = n >> 6, gate = (n >> 4) & 3, u = n & 15;
    int r = gate * 1024 + nb * 16 + u;
    float v = (k < 1024) ? Wih2[(size_t)r * 1024 + k]
                         : Whh2[(size_t)r * 1024 + (k - 1024)];
    B2[q] = (_Float16)v;
  } else if (e < S0 + 2 * S1 + 40960) {
    int q = (int)(e - S0 - 2 * S1);
    int n = q / 10, k = q - n * 10;
    int nb = n >> 6, gate = (n >> 4) & 3, u = n & 15;
    int r = gate * 1024 + nb * 16 + u;
    W0p[q] = Wih0[(size_t)r * 10 + k];
  } else if (e < S0 + 2 * S1 + 40960 + 12288) {
    int q = (int)(e - S0 - 2 * S1 - 40960);
    int l = q >> 12, n = q & 4095;
    int nb = n >> 6, gate = (n >> 4) & 3, u = n & 15;
    int r = gate * 1024 + nb * 16 + u;
    const float* bi = (l == 0) ? bih0 : (l == 1) ? bih1 : bih2;
    const float* bh = (l == 0) ? bhh0 : (l == 1) ? bhh1 : bhh2;
    biasP[q] = bi[r] + bh[r];
  }
}

// ---------------------------------------------------------------------------
// Encoder wavefront kernel: dispatch d computes L0@t=d, L1@t=d-1, L2@t=d-2.
// Grid (64, 12), 3 blocks/CU.
// ---------------------------------------------------------------------------
__global__ __launch_bounds__(256) void lstm_wave(
    int d,
    _Float16* __restrict__ h0p0, _Float16* __restrict__ h0p1,
    _Float16* __restrict__ h1p0, _Float16* __restrict__ h1p1,
    _Float16* __restrict__ h2p0, _Float16* __restrict__ h2p1,
    const _Float16* __restrict__ B0g, const _Float16* __restrict__ B1g,
    const _Float16* __restrict__ B2g,
    const float* __restrict__ biasP, const float* __restrict__ W0p,
    float* __restrict__ c0, float* __restrict__ c1, float* __restrict__ c2,
    const float* __restrict__ x, const int* __restrict__ xte,
    const float* __restrict__ e0, const float* __restrict__ e1,
    const float* __restrict__ e2, const float* __restrict__ e3)
{
  __shared__ __align__(16) char smem[32768];
  __shared__ float SmallIn[BM * SK];
  __shared__ float W0s[BN * 11];

  const int layer = blockIdx.y >> 2;
  const int mb = blockIdx.y & 3, nb = blockIdx.x;
  const int t = d - layer;
  if (t < 0 || t >= TSEQ) return;
  const int p = d & 1;

  const _Float16 *A1, *A2; _Float16* ho; const _Float16* Bm;
  const float* bias; float* cst; int Kdim;
  if (layer == 0) {
    A1 = p ? h0p1 : h0p0; A2 = A1;              ho = p ? h0p0 : h0p1;
    Bm = B0g; bias = biasP;        cst = c0; Kdim = 1024;
  } else if (layer == 1) {
    A1 = p ? h0p1 : h0p0; A2 = p ? h1p1 : h1p0; ho = p ? h1p0 : h1p1;
    Bm = B1g; bias = biasP + 4096; cst = c1; Kdim = 2048;
  } else {
    A1 = p ? h1p1 : h1p0; A2 = p ? h2p1 : h2p0; ho = p ? h2p0 : h2p1;
    Bm = B2g; bias = biasP + 8192; cst = c2; Kdim = 2048;
  }
  const int Mbase = mb * BM;
  const int tid = threadIdx.x;

  if (layer == 0 && tid < BM) {
    int Mg = Mbase + tid;
    float v[SK];
    const float* xp = x + ((size_t)Mg * TSEQ + t) * IND;
#pragma unroll
    for (int i = 0; i < IND; ++i) v[i] = xp[i];
    const int* ip = xte + ((size_t)Mg * TSEQ + t) * 4;
    int i0 = ip[0], i1 = ip[1], i2 = ip[2], i3 = ip[3];
#pragma unroll
    for (int dd = 0; dd < 3; ++dd)
      v[IND + dd] = e0[i0 * 3 + dd] + e1[i1 * 3 + dd] + e2[i2 * 3 + dd] + e3[i3 * 3 + dd];
#pragma unroll
    for (int i = 0; i < SK; ++i) SmallIn[tid * SK + i] = v[i];
    const float* wp = W0p + (size_t)(nb * BN + tid) * SK;
#pragma unroll
    for (int i = 0; i < SK; ++i) W0s[tid * 11 + i] = wp[i];
  }

  _Float16* As = (_Float16*)smem;
  _Float16* Bs = (_Float16*)(smem + 16384);

  const int w = tid >> 6, lane = tid & 63;
  const int quad = lane >> 4, l16 = lane & 15;
  const int dr = lane >> 4, ds = lane & 15;

  size_t a_goff[4], b_goff[4];
  int lds_off[4];
#pragma unroll
  for (int i = 0; i < 4; ++i) {
    int lrow = w * 16 + i * 4 + dr;
    int sg = ds ^ (i * 4 + dr);
    a_goff[i] = (size_t)(Mbase + lrow) * (HID * 2) + (size_t)sg * 16;
    b_goff[i] = (size_t)(nb * BN + lrow) * ((size_t)Kdim * 2) + (size_t)sg * 16;
    lds_off[i] = lrow * 256 + ds * 16;
  }

  f32x4 acc[4] = {};

  for (int kk = 0; kk < Kdim; kk += 128) {
    const char* Abase = (kk < 1024)
        ? ((const char*)A1 + (size_t)kk * 2)
        : ((const char*)A2 + (size_t)(kk - 1024) * 2);
    const char* Bbase = (const char*)Bm + (size_t)kk * 2;
#pragma unroll
    for (int i = 0; i < 4; ++i) {
      async_cp16(Abase + a_goff[i], smem + lds_off[i]);
      async_cp16(Bbase + b_goff[i], smem + 16384 + lds_off[i]);
    }
    __syncthreads();
#pragma unroll
    for (int ks = 0; ks < 4; ++ks) {
      int segq = (ks * 4 + quad) ^ l16;
      f16x8 bf = *reinterpret_cast<const f16x8*>(Bs + (w * 16 + l16) * 128 + segq * 8);
#pragma unroll
      for (int mt = 0; mt < 4; ++mt) {
        f16x8 af = *reinterpret_cast<const f16x8*>(As + (mt * 16 + l16) * 128 + segq * 8);
        acc[mt] = __builtin_amdgcn_mfma_f32_16x16x32_f16(af, bf, acc[mt], 0, 0, 0);
      }
    }
    __syncthreads();
  }

  float* Gs = (float*)smem;
#pragma unroll
  for (int mt = 0; mt < 4; ++mt) {
    int row = mt * 16 + quad * 4;
    int col = w * 16 + l16;
#pragma unroll
    for (int r = 0; r < 4; ++r)
      Gs[(row + r) * GSTR + col] = acc[mt][r];
  }
  __syncthreads();

#pragma unroll
  for (int i = 0; i < 4; ++i) {
    int m = (tid >> 4) + i * 16;
    int u = tid & 15;
    float gi = Gs[m * GSTR + u];
    float gf = Gs[m * GSTR + 16 + u];
    float gg = Gs[m * GSTR + 32 + u];
    float go = Gs[m * GSTR + 48 + u];
    int nbase = nb * BN;
    gi += bias[nbase + u];
    gf += bias[nbase + 16 + u];
    gg += bias[nbase + 32 + u];
    go += bias[nbase + 48 + u];
    if (layer == 0) {
#pragma unroll
      for (int k = 0; k < SK; ++k) {
        float sv = SmallIn[m * SK + k];
        gi += sv * W0s[u * 11 + k];
        gf += sv * W0s[(16 + u) * 11 + k];
        gg += sv * W0s[(32 + u) * 11 + k];
        go += sv * W0s[(48 + u) * 11 + k];
      }
    }
    size_t cidx = (size_t)(Mbase + m) * HID + (size_t)nb * 16 + u;
    float cold = cst[cidx];
    float cn = sigmoidf_fast(gf) * cold + sigmoidf_fast(gi) * tanhf_fast(gg);
    float hn = sigmoidf_fast(go) * tanhf_fast(cn);
    cst[cidx] = cn;
    ho[cidx] = (_Float16)hn;
  }
}

// ---------------------------------------------------------------------------
// Persistent-decoder layer body. BK=128 chunks, 4x32KB LDS bufs, depth-3,
// fine-grained vmcnt. MODE 1: L0 (+small input). MODE 2: deep. MODE 3: deep
// + fused fc -> atomicAdd out[:, s+1, :].
// ---------------------------------------------------------------------------
template<int KC, int MODE>
__device__ __forceinline__ void dec_layer(
    const char* A1, const char* A2, const char* Bm,
    const int* a_off, const int* b_off, const int* l_off,
    char* smem, float* Gs, const float* SmallIn, const float* W0s,
    const float* biasg, float* creg, _Float16* hout, float* out,
    const float* w7, const float* fcadd, int s, int Mbase, int nb, int tid)
{
  const int w = tid >> 6, lane = tid & 63;
  const int quad = lane >> 4, l16 = lane & 15;
  f32x4 acc[4] = {};

#define DISSUE(c) do { \
    const char* Ab_ = (KC == 8 || (c) < 8) ? (A1 + (size_t)(c) * 256) \
                                           : (A2 + (size_t)((c) - 8) * 256); \
    const char* Bb_ = Bm + (size_t)(c) * 256; \
    char* Lb_ = smem + ((c) % 4) * 32768; \
    _Pragma("unroll") \
    for (int i_ = 0; i_ < 4; ++i_) { \
      async_cp16(Ab_ + a_off[i_], Lb_ + l_off[i_]); \
      async_cp16(Bb_ + b_off[i_], Lb_ + 16384 + l_off[i_]); \
    } } while (0)

  DISSUE(0);
  DISSUE(1);
  DISSUE(2);
#pragma unroll
  for (int c = 0; c < KC; ++c) {
    if (c + 3 < KC)       { DISSUE(c + 3); WBAR(24); }
    else if (c + 3 == KC) { WBAR(16); }
    else if (c + 2 == KC) { WBAR(8); }
    else                  { WBAR(0); }
    const _Float16* As = (const _Float16*)(smem + (c % 4) * 32768);
    const _Float16* Bs = As + 8192;
#pragma unroll
    for (int ks = 0; ks < 4; ++ks) {
      int sq = (ks * 4 + quad) ^ l16;
      f16x8 bf = *reinterpret_cast<const f16x8*>(Bs + (w * 16 + l16) * 128 + sq * 8);
#pragma unroll
      for (int mt = 0; mt < 4; ++mt) {
        f16x8 af = *reinterpret_cast<const f16x8*>(As + (mt * 16 + l16) * 128 + sq * 8);
        acc[mt] = __builtin_amdgcn_mfma_f32_16x16x32_f16(af, bf, acc[mt], 0, 0, 0);
      }
    }
    BARO();   // buffer-recycle guard
  }
#undef DISSUE

#pragma unroll
  for (int mt = 0; mt < 4; ++mt) {
    int row = mt * 16 + quad * 4;
    int col = w * 16 + l16;
#pragma unroll
    for (int r = 0; r < 4; ++r)
      Gs[(row + r) * GSTR + col] = acc[mt][r];
  }
  __syncthreads();

#pragma unroll
  for (int i = 0; i < 4; ++i) {
    int m = (tid >> 4) + i * 16;
    int u = tid & 15;
    float gi = Gs[m * GSTR + u]      + biasg[0];
    float gf = Gs[m * GSTR + 16 + u] + biasg[1];
    float gg = Gs[m * GSTR + 32 + u] + biasg[2];
    float go = Gs[m * GSTR + 48 + u] + biasg[3];
    if (MODE == 1) {
#pragma unroll
      for (int k = 0; k < SK; ++k) {
        float sv = SmallIn[m * SK + k];
        gi += sv * W0s[u * 11 + k];
        gf += sv * W0s[(16 + u) * 11 + k];
        gg += sv * W0s[(32 + u) * 11 + k];
        go += sv * W0s[(48 + u) * 11 + k];
      }
    }
    float cn = sigmoidf_fast(gf) * creg[i] + sigmoidf_fast(gi) * tanhf_fast(gg);
    float hn = sigmoidf_fast(go) * tanhf_fast(cn);
    creg[i] = cn;
    hout[(size_t)(Mbase + m) * HID + (size_t)nb * 16 + u] = (_Float16)hn;
    if (MODE == 3) {
#pragma unroll
      for (int o = 0; o < OUTD; ++o) {
        float r = hn * w7[o];
        r += __shfl_xor(r, 1, 16);
        r += __shfl_xor(r, 2, 16);
        r += __shfl_xor(r, 4, 16);
        r += __shfl_xor(r, 8, 16);
        if (u == 0)
          atomicAdd(&out[(size_t)(Mbase + m) * (PRED * OUTD) + (s + 1) * OUTD + o],
                    r + fcadd[o]);
      }
    }
  }
}

// ---------------------------------------------------------------------------
// Persistent decoder: ONE kernel runs all 95 steps x 3 layers with
// device-wide flag barriers. Grid 256 blocks (nb = id&63 -> XCD-stable),
// LDS ~150KB -> 1 block/CU -> all blocks co-resident (manual barrier safe).
// c-state, bias, fcW slice live in registers across all steps.
// ---------------------------------------------------------------------------
__global__ __launch_bounds__(256, 1) void lstm_dec(
    _Float16* __restrict__ h0a, _Float16* __restrict__ h0b,
    _Float16* __restrict__ h1a, _Float16* __restrict__ h1b,
    _Float16* __restrict__ h2a, _Float16* __restrict__ h2b,
    const _Float16* __restrict__ B0g, const _Float16* __restrict__ B1g,
    const _Float16* __restrict__ B2g,
    const float* __restrict__ biasP, const float* __restrict__ W0p,
    const float* __restrict__ cbuf,
    float* __restrict__ out, const int* __restrict__ yte,
    const float* __restrict__ e0, const float* __restrict__ e1,
    const float* __restrict__ e2, const float* __restrict__ e3,
    const float* __restrict__ fcW, const float* __restrict__ fcb,
    unsigned* __restrict__ flags, unsigned* __restrict__ go_w)
{
  __shared__ __align__(16) char smem[4 * 32768];   // 128 KB staging
  __shared__ float Gs[BM * GSTR];                  // 17 KB
  __shared__ float SmallIn[BM * SK];
  __shared__ float W0s[BN * 11];

  const int tid = threadIdx.x;
  const int nb = blockIdx.x & 63, mb = blockIdx.x >> 6;
  const int Mbase = mb * BM;
  const int w = tid >> 6, lane = tid & 63;
  const int dr = lane >> 4, ds = lane & 15;

  int a_off[4], b1_off[4], b2_off[4], l_off[4];
#pragma unroll
  for (int i = 0; i < 4; ++i) {
    int lrow = w * 16 + i * 4 + dr;
    int sg = ds ^ (i * 4 + dr);
    a_off[i]  = (Mbase + lrow) * 2048 + sg * 16;
    b1_off[i] = (nb * 64 + lrow) * 2048 + sg * 16;
    b2_off[i] = (nb * 64 + lrow) * 4096 + sg * 16;
    l_off[i]  = lrow * 256 + ds * 16;
  }

  if (tid < BN) {
    const float* wp = W0p + (size_t)(nb * BN + tid) * SK;
#pragma unroll
    for (int i = 0; i < SK; ++i) W0s[tid * 11 + i] = wp[i];
  }

  const int u = tid & 15;
  float biasr[3][4];
#pragma unroll
  for (int l = 0; l < 3; ++l)
#pragma unroll
    for (int g = 0; g < 4; ++g)
      biasr[l][g] = biasP[l * 4096 + nb * 64 + g * 16 + u];

  float creg[3][4];
#pragma unroll
  for (int l = 0; l < 3; ++l)
#pragma unroll
    for (int i = 0; i < 4; ++i) {
      int m = (tid >> 4) + i * 16;
      creg[l][i] = cbuf[(size_t)l * 262144 + (size_t)(Mbase + m) * HID + nb * 16 + u];
    }

  float w7[OUTD], fcadd[OUTD];
#pragma unroll
  for (int o = 0; o < OUTD; ++o) {
    w7[o] = fcW[(size_t)o * HID + nb * 16 + u];
    fcadd[o] = (nb == 0) ? fcb[o] : 0.0f;
  }

  _Float16* h0[2] = {h0a, h0b};
  _Float16* h1[2] = {h1a, h1b};
  _Float16* h2[2] = {h2a, h2b};
  int p0 = 0, p1 = 1, p2 = 0;   // encoder handoff parities
  unsigned bc = 0;

  for (int s = 0; s < PRED - 1; ++s) {
    // small input for L0 (reads y_s from out, written by prev step / fc_kernel)
    if (tid < BM) {
      int Mg = Mbase + tid;
      float v[SK];
      const float* yp = out + (size_t)Mg * (PRED * OUTD) + s * OUTD;
#pragma unroll
      for (int i = 0; i < OUTD; ++i) v[i] = yp[i];
      const int* ip = yte + ((size_t)Mg * PRED + s) * 4;
      int i0 = ip[0], i1 = ip[1], i2 = ip[2], i3 = ip[3];
#pragma unroll
      for (int dd = 0; dd < 3; ++dd)
        v[IND + dd] = e0[i0 * 3 + dd] + e1[i1 * 3 + dd] + e2[i2 * 3 + dd] + e3[i3 * 3 + dd];
#pragma unroll
      for (int i = 0; i < SK; ++i) SmallIn[tid * SK + i] = v[i];
    }

    dec_layer<8, 1>((const char*)h0[p0], (const char*)h0[p0], (const char*)B0g,
                    a_off, b1_off, l_off, smem, Gs, SmallIn, W0s,
                    biasr[0], creg[0], h0[1 - p0], out, w7, fcadd, s, Mbase, nb, tid);
    gridbar(flags, go_w, ++bc);

    dec_layer<16, 2>((const char*)h0[1 - p0], (const char*)h1[p1], (const char*)B1g,
                     a_off, b2_off, l_off, smem, Gs, SmallIn, W0s,
                     biasr[1], creg[1], h1[1 - p1], out, w7, fcadd, s, Mbase, nb, tid);
    gridbar(flags, go_w, ++bc);

    dec_layer<16, 3>((const char*)h1[1 - p1], (const char*)h2[p2], (const char*)B2g,
                     a_off, b2_off, l_off, smem, Gs, SmallIn, W0s,
                     biasr[2], creg[2], h2[1 - p2], out, w7, fcadd, s, Mbase, nb, tid);
    gridbar(flags, go_w, ++bc);

    p0 ^= 1; p1 ^= 1; p2 ^= 1;
  }
}

// ---------------------------------------------------------------------------
// Standalone FC head for y0 only: y = h2 @ fcW^T + fcb -> out[:,0,:].
// ---------------------------------------------------------------------------
__global__ __launch_bounds__(256) void fc_kernel(
    const _Float16* __restrict__ h2, const float* __restrict__ fcW,
    const float* __restrict__ fcb, float* __restrict__ out)
{
  int wv = threadIdx.x >> 6, lane = threadIdx.x & 63;
  int row = blockIdx.x * 4 + wv;
  const _Float16* hp = h2 + (size_t)row * HID + lane * 16;
  float hv[16];
#pragma unroll
  for (int i = 0; i < 16; ++i) hv[i] = (float)hp[i];
  float acc[OUTD];
#pragma unroll
  for (int o = 0; o < OUTD; ++o) {
    const float* wp = fcW + (size_t)o * HID + lane * 16;
    float a = 0.f;
#pragma unroll
    for (int i = 0; i < 16; ++i) a += hv[i] * wp[i];
    acc[o] = a;
  }
#pragma unroll
  for (int o = 0; o < OUTD; ++o)
#pragma unroll
    for (int off = 32; off >= 1; off >>= 1)
      acc[o] += __shfl_xor(acc[o], off, 64);
  if (lane == 0) {
#pragma unroll
    for (int o = 0; o < OUTD; ++o)
      out[(size_t)row * (PRED * OUTD) + o] = acc[o] + fcb[o];
  }
}

// ---------------------------------------------------------------------------
// Workspace layout (bytes):
//   B0 @0 (8 MB) | B1 @8388608 (16 MB) | B2 @25165824 (16 MB)
//   W0p @41943040 | biasP @42106880
//   h par0 @42156032 (1.5 MB) + c @43728896 (3 MB)  } one memset
//   h par1 @46874624 (1.5 MB)                        } second memset
//   flags @48447488 (256 x 128 B = 32768) | go @48480256 (4 B)
// ---------------------------------------------------------------------------
extern "C" void kernel_launch(void* const* d_in, const int* in_sizes, int n_in,
                              void* d_out, int out_size, void* d_ws, size_t ws_size,
                              hipStream_t stream) {
  const float* x   = (const float*)d_in[0];
  const int*   xte = (const int*)d_in[2];
  const int*   yte = (const int*)d_in[3];
  const float* e0  = (const float*)d_in[4];
  const float* e1  = (const float*)d_in[5];
  const float* e2  = (const float*)d_in[6];
  const float* e3  = (const float*)d_in[7];
  const float* Wih0 = (const float*)d_in[8];
  const float* Whh0 = (const float*)d_in[9];
  const float* bih0 = (const float*)d_in[10];
  const float* bhh0 = (const float*)d_in[11];
  const float* Wih1 = (const float*)d_in[12];
  const float* Whh1 = (const float*)d_in[13];
  const float* bih1 = (const float*)d_in[14];
  const float* bhh1 = (const float*)d_in[15];
  const float* Wih2 = (const float*)d_in[16];
  const float* Whh2 = (const float*)d_in[17];
  const float* bih2 = (const float*)d_in[18];
  const float* bhh2 = (const float*)d_in[19];
  const float* fcW = (const float*)d_in[20];
  const float* fcb = (const float*)d_in[21];
  float* out = (float*)d_out;

  char* ws = (char*)d_ws;
  _Float16* B0   = (_Float16*)(ws);
  _Float16* B1   = (_Float16*)(ws + 8388608);
  _Float16* B2   = (_Float16*)(ws + 25165824);
  float*    W0p  = (float*)(ws + 41943040);
  float*    biasP= (float*)(ws + 42106880);
  char*     hp0  = ws + 42156032;
  float*    cbuf = (float*)(ws + 43728896);
  char*     hp1  = ws + 46874624;
  unsigned* flags= (unsigned*)(ws + 48447488);
  unsigned* go_w = (unsigned*)(ws + 48480256);

  hipMemsetAsync(out, 0, (size_t)out_size * 4, stream);
  hipMemsetAsync(hp0, 0, 4718592, stream);
  hipMemsetAsync(hp1, 0, 1572864, stream);
  hipMemsetAsync(flags, 0, 32772, stream);   // flags + go

  prep_kernel<<<82128, 256, 0, stream>>>(Wih0, Whh0, bih0, bhh0,
                                         Wih1, Whh1, bih1, bhh1,
                                         Wih2, Whh2, bih2, bhh2,
                                         B0, B1, B2, W0p, biasP);

  auto hb = [&](int l, int par) -> _Float16* {
    return (_Float16*)((par ? hp1 : hp0) + (size_t)l * 524288);
  };
  float* cl[3] = {cbuf, cbuf + 262144, cbuf + 524288};

  // encoder: wavefront over (layer, t) diagonals
  for (int d = 0; d < TSEQ + 2; ++d) {
    lstm_wave<<<dim3(64, 12), 256, 0, stream>>>(
        d, hb(0,0), hb(0,1), hb(1,0), hb(1,1), hb(2,0), hb(2,1),
        B0, B1, B2, biasP, W0p, cl[0], cl[1], cl[2],
        x, xte, e0, e1, e2, e3);
  }

  // handoff parities: h0@127 -> par0, h1@127 -> par1, h2@127 -> par0
  fc_kernel<<<64, 256, 0, stream>>>(hb(2,0), fcW, fcb, out);   // y0

  lstm_dec<<<256, 256, 0, stream>>>(
      hb(0,0), hb(0,1), hb(1,0), hb(1,1), hb(2,0), hb(2,1),
      B0, B1, B2, biasP, W0p, cbuf,
      out, yte, e0, e1, e2, e3, fcW, fcb, flags, go_w);
}

// Round 8
// 8061.358 us; speedup vs baseline: 2.6120x; 2.2142x over previous
//
#include <hip/hip_runtime.h>

#define HID   1024
#define BATCH 256
#define TSEQ  128
#define PRED  96
#define IND   7
#define OUTD  7
#define SK    10   // small input dim: 7 features + 3 time-encode dims

typedef __attribute__((ext_vector_type(8))) _Float16 f16x8;
typedef __attribute__((ext_vector_type(4))) float    f32x4;

#define BM   64
#define BN   64
#define GSTR 68    // gates LDS stride (floats), <=2-way bank aliasing (free)

// CPol bits (gfx950): SC0=1, NT=2, SC1=16. SC0|SC1=17 -> bypass L1+L2,
// read/write at the coherence point (cross-XCD coherent, no invalidates).
#define AUX_COH 17

__device__ __forceinline__ float sigmoidf_fast(float x) {
  return 1.0f / (1.0f + __expf(-x));
}
__device__ __forceinline__ float tanhf_fast(float x) {
  float ax = fabsf(x);
  float e  = __expf(-2.0f * ax);
  float r  = (1.0f - e) / (1.0f + e);
  return copysignf(r, x);
}

template<int AUX>
__device__ __forceinline__ void async_cp16(const void* g, void* l) {
  __builtin_amdgcn_global_load_lds(
      (const __attribute__((address_space(1))) void*)g,
      (__attribute__((address_space(3))) void*)l, 16, 0, AUX);
}

// fine-grained wait + barrier (pipeline): NEVER vmcnt(0) mid-loop
#define WBAR(N) asm volatile("s_waitcnt vmcnt(" #N ")\n\ts_barrier" ::: "memory")
#define BARO()  asm volatile("s_barrier" ::: "memory")

// Device-wide barrier v4: pure flags, NO FENCES.
//  R4-R6 history: atomic-RMW counter + threadfence pair ~50us/barrier-phase.
//  R7: flag barrier (no RMW) but kept __threadfence -> acquire buffer_inv
//  blows the entire L2 (incl. 2MB read-only weights) every phase -> 35MB/step
//  refetch (FETCH 3.3GB/dispatch), phases ~49us.
//  R8: coherence moved to the DATA (h stores/loads are system-scope), so the
//  barrier needs no cache maintenance at all. Weights stay L2-resident.
// Safe: 256 blocks, 154KB LDS -> 1 block/CU -> all co-resident.
__device__ __forceinline__ void gridbar(unsigned* flags, unsigned* go,
                                        unsigned bc) {
  __syncthreads();   // all waves' stores drained (vmcnt) before flagging
  const int tid = threadIdx.x;
  if (blockIdx.x == 0) {
    if (tid > 0) {                 // thread tid waits for block tid's arrival
      while (__hip_atomic_load(flags + tid * 32,
                               __ATOMIC_RELAXED, __HIP_MEMORY_SCOPE_SYSTEM) < bc)
        __builtin_amdgcn_s_sleep(1);
    }
    __syncthreads();
    if (tid == 0)
      __hip_atomic_store(go, bc, __ATOMIC_RELAXED, __HIP_MEMORY_SCOPE_SYSTEM);
  } else {
    if (tid == 0) {
      __hip_atomic_store(flags + blockIdx.x * 32, bc,
                         __ATOMIC_RELAXED, __HIP_MEMORY_SCOPE_SYSTEM);
      while (__hip_atomic_load(go, __ATOMIC_RELAXED,
                               __HIP_MEMORY_SCOPE_SYSTEM) < bc)
        __builtin_amdgcn_s_sleep(1);
    }
    __syncthreads();
  }
}

// ---------------------------------------------------------------------------
// Weight prep: fp16 B [n][k], n = nb*64 + gate*16 + u <-> r = gate*1024+nb*16+u
// ---------------------------------------------------------------------------
__global__ __launch_bounds__(256) void prep_kernel(
    const float* __restrict__ Wih0, const float* __restrict__ Whh0,
    const float* __restrict__ bih0, const float* __restrict__ bhh0,
    const float* __restrict__ Wih1, const float* __restrict__ Whh1,
    const float* __restrict__ bih1, const float* __restrict__ bhh1,
    const float* __restrict__ Wih2, const float* __restrict__ Whh2,
    const float* __restrict__ bih2, const float* __restrict__ bhh2,
    _Float16* __restrict__ B0, _Float16* __restrict__ B1, _Float16* __restrict__ B2,
    float* __restrict__ W0p, float* __restrict__ biasP)
{
  size_t e = (size_t)blockIdx.x * 256 + threadIdx.x;
  const size_t S0 = (size_t)4096 * 1024;
  const size_t S1 = (size_t)4096 * 2048;
  if (e < S0) {
    int n = (int)(e >> 10), k = (int)(e & 1023);
    int nb = n >> 6, gate = (n >> 4) & 3, u = n & 15;
    int r = gate * 1024 + nb * 16 + u;
    B0[e] = (_Float16)Whh0[(size_t)r * 1024 + k];
  } else if (e < S0 + S1) {
    size_t q = e - S0;
    int n = (int)(q >> 11), k = (int)(q & 2047);
    int nb = n >> 6, gate = (n >> 4) & 3, u = n & 15;
    int r = gate * 1024 + nb * 16 + u;
    float v = (k < 1024) ? Wih1[(size_t)r * 1024 + k]
                         : Whh1[(size_t)r * 1024 + (k - 1024)];
    B1[q] = (_Float16)v;
  } else if (e < S0 + 2 * S1) {
    size_t q = e - S0 - S1;
    int n = (int)(q >> 11), k = (int)(q & 2047);
    int nb = n >> 6, gate = (n >> 4) & 3, u = n & 15;
    int r = gate * 1024 + nb * 16 + u;
    float v = (k < 1024) ? Wih2[(size_t)r * 1024 + k]
                         : Whh2[(size_t)r * 1024 + (k - 1024)];
    B2[q] = (_Float16)v;
  } else if (e < S0 + 2 * S1 + 40960) {
    int q = (int)(e - S0 - 2 * S1);
    int n = q / 10, k = q - n * 10;
    int nb = n >> 6, gate = (n >> 4) & 3, u = n & 15;
    int r = gate * 1024 + nb * 16 + u;
    W0p[q] = Wih0[(size_t)r * 10 + k];
  } else if (e < S0 + 2 * S1 + 40960 + 12288) {
    int q = (int)(e - S0 - 2 * S1 - 40960);
    int l = q >> 12, n = q & 4095;
    int nb = n >> 6, gate = (n >> 4) & 3, u = n & 15;
    int r = gate * 1024 + nb * 16 + u;
    const float* bi = (l == 0) ? bih0 : (l == 1) ? bih1 : bih2;
    const float* bh = (l == 0) ? bhh0 : (l == 1) ? bhh1 : bhh2;
    biasP[q] = bi[r] + bh[r];
  }
}

// ---------------------------------------------------------------------------
// Encoder wavefront kernel: dispatch d computes L0@t=d, L1@t=d-1, L2@t=d-2.
// Grid (64, 12), 3 blocks/CU. Normal cached loads/stores (kernel boundaries
// provide the release/acquire between dispatches).
// ---------------------------------------------------------------------------
__global__ __launch_bounds__(256) void lstm_wave(
    int d,
    _Float16* __restrict__ h0p0, _Float16* __restrict__ h0p1,
    _Float16* __restrict__ h1p0, _Float16* __restrict__ h1p1,
    _Float16* __restrict__ h2p0, _Float16* __restrict__ h2p1,
    const _Float16* __restrict__ B0g, const _Float16* __restrict__ B1g,
    const _Float16* __restrict__ B2g,
    const float* __restrict__ biasP, const float* __restrict__ W0p,
    float* __restrict__ c0, float* __restrict__ c1, float* __restrict__ c2,
    const float* __restrict__ x, const int* __restrict__ xte,
    const float* __restrict__ e0, const float* __restrict__ e1,
    const float* __restrict__ e2, const float* __restrict__ e3)
{
  __shared__ __align__(16) char smem[32768];
  __shared__ float SmallIn[BM * SK];
  __shared__ float W0s[BN * 11];

  const int layer = blockIdx.y >> 2;
  const int mb = blockIdx.y & 3, nb = blockIdx.x;
  const int t = d - layer;
  if (t < 0 || t >= TSEQ) return;
  const int p = d & 1;

  const _Float16 *A1, *A2; _Float16* ho; const _Float16* Bm;
  const float* bias; float* cst; int Kdim;
  if (layer == 0) {
    A1 = p ? h0p1 : h0p0; A2 = A1;              ho = p ? h0p0 : h0p1;
    Bm = B0g; bias = biasP;        cst = c0; Kdim = 1024;
  } else if (layer == 1) {
    A1 = p ? h0p1 : h0p0; A2 = p ? h1p1 : h1p0; ho = p ? h1p0 : h1p1;
    Bm = B1g; bias = biasP + 4096; cst = c1; Kdim = 2048;
  } else {
    A1 = p ? h1p1 : h1p0; A2 = p ? h2p1 : h2p0; ho = p ? h2p0 : h2p1;
    Bm = B2g; bias = biasP + 8192; cst = c2; Kdim = 2048;
  }
  const int Mbase = mb * BM;
  const int tid = threadIdx.x;

  if (layer == 0 && tid < BM) {
    int Mg = Mbase + tid;
    float v[SK];
    const float* xp = x + ((size_t)Mg * TSEQ + t) * IND;
#pragma unroll
    for (int i = 0; i < IND; ++i) v[i] = xp[i];
    const int* ip = xte + ((size_t)Mg * TSEQ + t) * 4;
    int i0 = ip[0], i1 = ip[1], i2 = ip[2], i3 = ip[3];
#pragma unroll
    for (int dd = 0; dd < 3; ++dd)
      v[IND + dd] = e0[i0 * 3 + dd] + e1[i1 * 3 + dd] + e2[i2 * 3 + dd] + e3[i3 * 3 + dd];
#pragma unroll
    for (int i = 0; i < SK; ++i) SmallIn[tid * SK + i] = v[i];
    const float* wp = W0p + (size_t)(nb * BN + tid) * SK;
#pragma unroll
    for (int i = 0; i < SK; ++i) W0s[tid * 11 + i] = wp[i];
  }

  _Float16* As = (_Float16*)smem;
  _Float16* Bs = (_Float16*)(smem + 16384);

  const int w = tid >> 6, lane = tid & 63;
  const int quad = lane >> 4, l16 = lane & 15;
  const int dr = lane >> 4, ds = lane & 15;

  size_t a_goff[4], b_goff[4];
  int lds_off[4];
#pragma unroll
  for (int i = 0; i < 4; ++i) {
    int lrow = w * 16 + i * 4 + dr;
    int sg = ds ^ (i * 4 + dr);
    a_goff[i] = (size_t)(Mbase + lrow) * (HID * 2) + (size_t)sg * 16;
    b_goff[i] = (size_t)(nb * BN + lrow) * ((size_t)Kdim * 2) + (size_t)sg * 16;
    lds_off[i] = lrow * 256 + ds * 16;
  }

  f32x4 acc[4] = {};

  for (int kk = 0; kk < Kdim; kk += 128) {
    const char* Abase = (kk < 1024)
        ? ((const char*)A1 + (size_t)kk * 2)
        : ((const char*)A2 + (size_t)(kk - 1024) * 2);
    const char* Bbase = (const char*)Bm + (size_t)kk * 2;
#pragma unroll
    for (int i = 0; i < 4; ++i) {
      async_cp16<0>(Abase + a_goff[i], smem + lds_off[i]);
      async_cp16<0>(Bbase + b_goff[i], smem + 16384 + lds_off[i]);
    }
    __syncthreads();
#pragma unroll
    for (int ks = 0; ks < 4; ++ks) {
      int segq = (ks * 4 + quad) ^ l16;
      f16x8 bf = *reinterpret_cast<const f16x8*>(Bs + (w * 16 + l16) * 128 + segq * 8);
#pragma unroll
      for (int mt = 0; mt < 4; ++mt) {
        f16x8 af = *reinterpret_cast<const f16x8*>(As + (mt * 16 + l16) * 128 + segq * 8);
        acc[mt] = __builtin_amdgcn_mfma_f32_16x16x32_f16(af, bf, acc[mt], 0, 0, 0);
      }
    }
    __syncthreads();
  }

  float* Gs = (float*)smem;
#pragma unroll
  for (int mt = 0; mt < 4; ++mt) {
    int row = mt * 16 + quad * 4;
    int col = w * 16 + l16;
#pragma unroll
    for (int r = 0; r < 4; ++r)
      Gs[(row + r) * GSTR + col] = acc[mt][r];
  }
  __syncthreads();

#pragma unroll
  for (int i = 0; i < 4; ++i) {
    int m = (tid >> 4) + i * 16;
    int u = tid & 15;
    float gi = Gs[m * GSTR + u];
    float gf = Gs[m * GSTR + 16 + u];
    float gg = Gs[m * GSTR + 32 + u];
    float go = Gs[m * GSTR + 48 + u];
    int nbase = nb * BN;
    gi += bias[nbase + u];
    gf += bias[nbase + 16 + u];
    gg += bias[nbase + 32 + u];
    go += bias[nbase + 48 + u];
    if (layer == 0) {
#pragma unroll
      for (int k = 0; k < SK; ++k) {
        float sv = SmallIn[m * SK + k];
        gi += sv * W0s[u * 11 + k];
        gf += sv * W0s[(16 + u) * 11 + k];
        gg += sv * W0s[(32 + u) * 11 + k];
        go += sv * W0s[(48 + u) * 11 + k];
      }
    }
    size_t cidx = (size_t)(Mbase + m) * HID + (size_t)nb * 16 + u;
    float cold = cst[cidx];
    float cn = sigmoidf_fast(gf) * cold + sigmoidf_fast(gi) * tanhf_fast(gg);
    float hn = sigmoidf_fast(go) * tanhf_fast(cn);
    cst[cidx] = cn;
    ho[cidx] = (_Float16)hn;
  }
}

// ---------------------------------------------------------------------------
// Persistent-decoder layer body. BK=128 chunks, 4x32KB LDS bufs, depth-3.
// A (= h, cross-block fresh data) staged with AUX_COH (bypass L1/L2, read
// coherence point). B (weights, read-only) staged cached -> stays L2-resident
// across all 95 steps. h written with system-scope stores.
// MODE 1: L0 (+small input). MODE 2: deep. MODE 3: deep + fused fc.
// ---------------------------------------------------------------------------
template<int KC, int MODE>
__device__ __forceinline__ void dec_layer(
    const char* A1, const char* A2, const char* Bm,
    const int* a_off, const int* b_off, const int* l_off,
    char* smem, float* Gs, const float* SmallIn, const float* W0s,
    const float* biasg, float* creg, _Float16* hout, float* out,
    const float* w7, const float* fcadd, int s, int Mbase, int nb, int tid)
{
  const int w = tid >> 6, lane = tid & 63;
  const int quad = lane >> 4, l16 = lane & 15;
  f32x4 acc[4] = {};

#define DISSUE(c) do { \
    const char* Ab_ = (KC == 8 || (c) < 8) ? (A1 + (size_t)(c) * 256) \
                                           : (A2 + (size_t)((c) - 8) * 256); \
    const char* Bb_ = Bm + (size_t)(c) * 256; \
    char* Lb_ = smem + ((c) % 4) * 32768; \
    _Pragma("unroll") \
    for (int i_ = 0; i_ < 4; ++i_) { \
      async_cp16<AUX_COH>(Ab_ + a_off[i_], Lb_ + l_off[i_]); \
      async_cp16<0>(Bb_ + b_off[i_], Lb_ + 16384 + l_off[i_]); \
    } } while (0)

  DISSUE(0);
  DISSUE(1);
  DISSUE(2);
#pragma unroll
  for (int c = 0; c < KC; ++c) {
    if (c + 3 < KC)       { DISSUE(c + 3); WBAR(24); }
    else if (c + 3 == KC) { WBAR(16); }
    else if (c + 2 == KC) { WBAR(8); }
    else                  { WBAR(0); }
    const _Float16* As = (const _Float16*)(smem + (c % 4) * 32768);
    const _Float16* Bs = As + 8192;
#pragma unroll
    for (int ks = 0; ks < 4; ++ks) {
      int sq = (ks * 4 + quad) ^ l16;
      f16x8 bf = *reinterpret_cast<const f16x8*>(Bs + (w * 16 + l16) * 128 + sq * 8);
#pragma unroll
      for (int mt = 0; mt < 4; ++mt) {
        f16x8 af = *reinterpret_cast<const f16x8*>(As + (mt * 16 + l16) * 128 + sq * 8);
        acc[mt] = __builtin_amdgcn_mfma_f32_16x16x32_f16(af, bf, acc[mt], 0, 0, 0);
      }
    }
    BARO();   // buffer-recycle guard
  }
#undef DISSUE

#pragma unroll
  for (int mt = 0; mt < 4; ++mt) {
    int row = mt * 16 + quad * 4;
    int col = w * 16 + l16;
#pragma unroll
    for (int r = 0; r < 4; ++r)
      Gs[(row + r) * GSTR + col] = acc[mt][r];
  }
  __syncthreads();

#pragma unroll
  for (int i = 0; i < 4; ++i) {
    int m = (tid >> 4) + i * 16;
    int u = tid & 15;
    float gi = Gs[m * GSTR + u]      + biasg[0];
    float gf = Gs[m * GSTR + 16 + u] + biasg[1];
    float gg = Gs[m * GSTR + 32 + u] + biasg[2];
    float go = Gs[m * GSTR + 48 + u] + biasg[3];
    if (MODE == 1) {
#pragma unroll
      for (int k = 0; k < SK; ++k) {
        float sv = SmallIn[m * SK + k];
        gi += sv * W0s[u * 11 + k];
        gf += sv * W0s[(16 + u) * 11 + k];
        gg += sv * W0s[(32 + u) * 11 + k];
        go += sv * W0s[(48 + u) * 11 + k];
      }
    }
    float cn = sigmoidf_fast(gf) * creg[i] + sigmoidf_fast(gi) * tanhf_fast(gg);
    float hn = sigmoidf_fast(go) * tanhf_fast(cn);
    creg[i] = cn;
    // system-scope h store: write-through to coherence point (no dirty L2)
    union { _Float16 f; unsigned short us; } cv; cv.f = (_Float16)hn;
    __hip_atomic_store(
        (unsigned short*)(hout + (size_t)(Mbase + m) * HID + (size_t)nb * 16 + u),
        cv.us, __ATOMIC_RELAXED, __HIP_MEMORY_SCOPE_SYSTEM);
    if (MODE == 3) {
#pragma unroll
      for (int o = 0; o < OUTD; ++o) {
        float r = hn * w7[o];
        r += __shfl_xor(r, 1, 16);
        r += __shfl_xor(r, 2, 16);
        r += __shfl_xor(r, 4, 16);
        r += __shfl_xor(r, 8, 16);
        if (u == 0)
          atomicAdd(&out[(size_t)(Mbase + m) * (PRED * OUTD) + (s + 1) * OUTD + o],
                    r + fcadd[o]);
      }
    }
  }
}

// ---------------------------------------------------------------------------
// Persistent decoder: ONE kernel runs all 95 steps x 3 layers with fenceless
// flag barriers. Grid 256 blocks (nb = id&63 -> XCD-stable), ~154KB LDS ->
// 1 block/CU -> all co-resident. c-state, bias, fcW slice in registers.
// ---------------------------------------------------------------------------
__global__ __launch_bounds__(256, 1) void lstm_dec(
    _Float16* __restrict__ h0a, _Float16* __restrict__ h0b,
    _Float16* __restrict__ h1a, _Float16* __restrict__ h1b,
    _Float16* __restrict__ h2a, _Float16* __restrict__ h2b,
    const _Float16* __restrict__ B0g, const _Float16* __restrict__ B1g,
    const _Float16* __restrict__ B2g,
    const float* __restrict__ biasP, const float* __restrict__ W0p,
    const float* __restrict__ cbuf,
    float* __restrict__ out, const int* __restrict__ yte,
    const float* __restrict__ e0, const float* __restrict__ e1,
    const float* __restrict__ e2, const float* __restrict__ e3,
    const float* __restrict__ fcW, const float* __restrict__ fcb,
    unsigned* __restrict__ flags, unsigned* __restrict__ go_w)
{
  __shared__ __align__(16) char smem[4 * 32768];   // 128 KB staging
  __shared__ float Gs[BM * GSTR];                  // 17 KB
  __shared__ float SmallIn[BM * SK];
  __shared__ float W0s[BN * 11];

  const int tid = threadIdx.x;
  const int nb = blockIdx.x & 63, mb = blockIdx.x >> 6;
  const int Mbase = mb * BM;
  const int w = tid >> 6, lane = tid & 63;
  const int dr = lane >> 4, ds = lane & 15;

  int a_off[4], b1_off[4], b2_off[4], l_off[4];
#pragma unroll
  for (int i = 0; i < 4; ++i) {
    int lrow = w * 16 + i * 4 + dr;
    int sg = ds ^ (i * 4 + dr);
    a_off[i]  = (Mbase + lrow) * 2048 + sg * 16;
    b1_off[i] = (nb * 64 + lrow) * 2048 + sg * 16;
    b2_off[i] = (nb * 64 + lrow) * 4096 + sg * 16;
    l_off[i]  = lrow * 256 + ds * 16;
  }

  if (tid < BN) {
    const float* wp = W0p + (size_t)(nb * BN + tid) * SK;
#pragma unroll
    for (int i = 0; i < SK; ++i) W0s[tid * 11 + i] = wp[i];
  }

  const int u = tid & 15;
  float biasr[3][4];
#pragma unroll
  for (int l = 0; l < 3; ++l)
#pragma unroll
    for (int g = 0; g < 4; ++g)
      biasr[l][g] = biasP[l * 4096 + nb * 64 + g * 16 + u];

  float creg[3][4];
#pragma unroll
  for (int l = 0; l < 3; ++l)
#pragma unroll
    for (int i = 0; i < 4; ++i) {
      int m = (tid >> 4) + i * 16;
      creg[l][i] = cbuf[(size_t)l * 262144 + (size_t)(Mbase + m) * HID + nb * 16 + u];
    }

  float w7[OUTD], fcadd[OUTD];
#pragma unroll
  for (int o = 0; o < OUTD; ++o) {
    w7[o] = fcW[(size_t)o * HID + nb * 16 + u];
    fcadd[o] = (nb == 0) ? fcb[o] : 0.0f;
  }

  _Float16* h0[2] = {h0a, h0b};
  _Float16* h1[2] = {h1a, h1b};
  _Float16* h2[2] = {h2a, h2b};
  int p0 = 0, p1 = 1, p2 = 0;   // encoder handoff parities
  unsigned bc = 0;

  for (int s = 0; s < PRED - 1; ++s) {
    // small input for L0: y_s via system-scope loads (atomicAdd'd last step)
    if (tid < BM) {
      int Mg = Mbase + tid;
      float v[SK];
      const float* yp = out + (size_t)Mg * (PRED * OUTD) + s * OUTD;
#pragma unroll
      for (int i = 0; i < OUTD; ++i)
        v[i] = __hip_atomic_load(yp + i, __ATOMIC_RELAXED,
                                 __HIP_MEMORY_SCOPE_SYSTEM);
      const int* ip = yte + ((size_t)Mg * PRED + s) * 4;
      int i0 = ip[0], i1 = ip[1], i2 = ip[2], i3 = ip[3];
#pragma unroll
      for (int dd = 0; dd < 3; ++dd)
        v[IND + dd] = e0[i0 * 3 + dd] + e1[i1 * 3 + dd] + e2[i2 * 3 + dd] + e3[i3 * 3 + dd];
#pragma unroll
      for (int i = 0; i < SK; ++i) SmallIn[tid * SK + i] = v[i];
    }

    dec_layer<8, 1>((const char*)h0[p0], (const char*)h0[p0], (const char*)B0g,
                    a_off, b1_off, l_off, smem, Gs, SmallIn, W0s,
                    biasr[0], creg[0], h0[1 - p0], out, w7, fcadd, s, Mbase, nb, tid);
    gridbar(flags, go_w, ++bc);

    dec_layer<16, 2>((const char*)h0[1 - p0], (const char*)h1[p1], (const char*)B1g,
                     a_off, b2_off, l_off, smem, Gs, SmallIn, W0s,
                     biasr[1], creg[1], h1[1 - p1], out, w7, fcadd, s, Mbase, nb, tid);
    gridbar(flags, go_w, ++bc);

    dec_layer<16, 3>((const char*)h1[1 - p1], (const char*)h2[p2], (const char*)B2g,
                     a_off, b2_off, l_off, smem, Gs, SmallIn, W0s,
                     biasr[2], creg[2], h2[1 - p2], out, w7, fcadd, s, Mbase, nb, tid);
    gridbar(flags, go_w, ++bc);

    p0 ^= 1; p1 ^= 1; p2 ^= 1;
  }
}

// ---------------------------------------------------------------------------
// Standalone FC head for y0 only: y = h2 @ fcW^T + fcb -> out[:,0,:].
// ---------------------------------------------------------------------------
__global__ __launch_bounds__(256) void fc_kernel(
    const _Float16* __restrict__ h2, const float* __restrict__ fcW,
    const float* __restrict__ fcb, float* __restrict__ out)
{
  int wv = threadIdx.x >> 6, lane = threadIdx.x & 63;
  int row = blockIdx.x * 4 + wv;
  const _Float16* hp = h2 + (size_t)row * HID + lane * 16;
  float hv[16];
#pragma unroll
  for (int i = 0; i < 16; ++i) hv[i] = (float)hp[i];
  float acc[OUTD];
#pragma unroll
  for (int o = 0; o < OUTD; ++o) {
    const float* wp = fcW + (size_t)o * HID + lane * 16;
    float a = 0.f;
#pragma unroll
    for (int i = 0; i < 16; ++i) a += hv[i] * wp[i];
    acc[o] = a;
  }
#pragma unroll
  for (int o = 0; o < OUTD; ++o)
#pragma unroll
    for (int off = 32; off >= 1; off >>= 1)
      acc[o] += __shfl_xor(acc[o], off, 64);
  if (lane == 0) {
#pragma unroll
    for (int o = 0; o < OUTD; ++o)
      out[(size_t)row * (PRED * OUTD) + o] = acc[o] + fcb[o];
  }
}

// ---------------------------------------------------------------------------
// Workspace layout (bytes):
//   B0 @0 (8 MB) | B1 @8388608 (16 MB) | B2 @25165824 (16 MB)
//   W0p @41943040 | biasP @42106880
//   h par0 @42156032 (1.5 MB) + c @43728896 (3 MB)  } one memset
//   h par1 @46874624 (1.5 MB)                        } second memset
//   flags @48447488 (256 x 128 B = 32768) | go @48480256 (4 B)
// ---------------------------------------------------------------------------
extern "C" void kernel_launch(void* const* d_in, const int* in_sizes, int n_in,
                              void* d_out, int out_size, void* d_ws, size_t ws_size,
                              hipStream_t stream) {
  const float* x   = (const float*)d_in[0];
  const int*   xte = (const int*)d_in[2];
  const int*   yte = (const int*)d_in[3];
  const float* e0  = (const float*)d_in[4];
  const float* e1  = (const float*)d_in[5];
  const float* e2  = (const float*)d_in[6];
  const float* e3  = (const float*)d_in[7];
  const float* Wih0 = (const float*)d_in[8];
  const float* Whh0 = (const float*)d_in[9];
  const float* bih0 = (const float*)d_in[10];
  const float* bhh0 = (const float*)d_in[11];
  const float* Wih1 = (const float*)d_in[12];
  const float* Whh1 = (const float*)d_in[13];
  const float* bih1 = (const float*)d_in[14];
  const float* bhh1 = (const float*)d_in[15];
  const float* Wih2 = (const float*)d_in[16];
  const float* Whh2 = (const float*)d_in[17];
  const float* bih2 = (const float*)d_in[18];
  const float* bhh2 = (const float*)d_in[19];
  const float* fcW = (const float*)d_in[20];
  const float* fcb = (const float*)d_in[21];
  float* out = (float*)d_out;

  char* ws = (char*)d_ws;
  _Float16* B0   = (_Float16*)(ws);
  _Float16* B1   = (_Float16*)(ws + 8388608);
  _Float16* B2   = (_Float16*)(ws + 25165824);
  float*    W0p  = (float*)(ws + 41943040);
  float*    biasP= (float*)(ws + 42106880);
  char*     hp0  = ws + 42156032;
  float*    cbuf = (float*)(ws + 43728896);
  char*     hp1  = ws + 46874624;
  unsigned* flags= (unsigned*)(ws + 48447488);
  unsigned* go_w = (unsigned*)(ws + 48480256);

  hipMemsetAsync(out, 0, (size_t)out_size * 4, stream);
  hipMemsetAsync(hp0, 0, 4718592, stream);
  hipMemsetAsync(hp1, 0, 1572864, stream);
  hipMemsetAsync(flags, 0, 32772, stream);   // flags + go

  prep_kernel<<<82128, 256, 0, stream>>>(Wih0, Whh0, bih0, bhh0,
                                         Wih1, Whh1, bih1, bhh1,
                                         Wih2, Whh2, bih2, bhh2,
                                         B0, B1, B2, W0p, biasP);

  auto hb = [&](int l, int par) -> _Float16* {
    return (_Float16*)((par ? hp1 : hp0) + (size_t)l * 524288);
  };
  float* cl[3] = {cbuf, cbuf + 262144, cbuf + 524288};

  // encoder: wavefront over (layer, t) diagonals
  for (int d = 0; d < TSEQ + 2; ++d) {
    lstm_wave<<<dim3(64, 12), 256, 0, stream>>>(
        d, hb(0,0), hb(0,1), hb(1,0), hb(1,1), hb(2,0), hb(2,1),
        B0, B1, B2, biasP, W0p, cl[0], cl[1], cl[2],
        x, xte, e0, e1, e2, e3);
  }

  // handoff parities: h0@127 -> par0, h1@127 -> par1, h2@127 -> par0
  fc_kernel<<<64, 256, 0, stream>>>(hb(2,0), fcW, fcb, out);   // y0

  lstm_dec<<<256, 256, 0, stream>>>(
      hb(0,0), hb(0,1), hb(1,0), hb(1,1), hb(2,0), hb(2,1),
      B0, B1, B2, biasP, W0p, cbuf,
      out, yte, e0, e1, e2, e3, fcW, fcb, flags, go_w);
}